// Round 20
// baseline (1440.247 us; speedup 1.0000x reference)
//
#include <hip/hip_runtime.h>
#include <math.h>

#define BB 64
#define TT 257
#define DD 1024
#define HH 16
#define FF 4096
#define RR 16
#define HDD 64
#define TMM 241          // T - R
#define M1 (BB*TT)       // 16448
#define M2 (BB*TMM)      // 15424
#define NA 129
#define NB 128

typedef float f4v __attribute__((ext_vector_type(4)));
typedef short s8v __attribute__((ext_vector_type(8)));
typedef short s4v __attribute__((ext_vector_type(4)));
typedef unsigned short us;

__device__ __forceinline__ us f2bf(float f){
  unsigned u = __float_as_uint(f);
  u += 0x7fffu + ((u >> 16) & 1u);
  return (us)(u >> 16);
}
__device__ __forceinline__ float bf2f(us h){
  return __uint_as_float(((unsigned)h) << 16);
}
// truncation hi/lo split of a pair, packed into u32 words (low=f0, high=f1)
__device__ __forceinline__ void splitpk(float f0, float f1, unsigned &hp, unsigned &lp){
  unsigned u0 = __float_as_uint(f0), u1 = __float_as_uint(f1);
  unsigned h0m = u0 & 0xFFFF0000u, h1m = u1 & 0xFFFF0000u;
  hp = (u0 >> 16) | h1m;
  float l0 = f0 - __uint_as_float(h0m);
  float l1 = f1 - __uint_as_float(h1m);
  lp = (__float_as_uint(l0) >> 16) | (__float_as_uint(l1) & 0xFFFF0000u);
}
// single-value truncation split
__device__ __forceinline__ void split1(float f, us &h, us &l){
  unsigned u = __float_as_uint(f);
  unsigned hm = u & 0xFFFF0000u;
  h = (us)(u >> 16);
  l = (us)(__float_as_uint(f - __uint_as_float(hm)) >> 16);
}
// async global->LDS, 16B per lane; LDS dest = wave-uniform base + lane*16, global src per-lane
__device__ __forceinline__ void gl16(const us* g, us* l){
  __builtin_amdgcn_global_load_lds((const __attribute__((address_space(1))) void*)g,
                                   (__attribute__((address_space(3))) void*)l, 16, 0, 0);
}

// ---------------- per-row LN stats (mu, rstd) ----------------
__global__ __launch_bounds__(64) void lnstats_kernel(const float* __restrict__ x,
                                                     float* __restrict__ st)
{
  int row = blockIdx.x, lane = threadIdx.x;
  const float* p = x + (size_t)row * DD;
  float s = 0.0f, sq = 0.0f;
  #pragma unroll
  for (int i = 0; i < 4; i++){
    float4 v = *(const float4*)(p + i * 256 + lane * 4);
    s  += v.x + v.y + v.z + v.w;
    sq += v.x*v.x + v.y*v.y + v.z*v.z + v.w*v.w;
  }
  #pragma unroll
  for (int m = 1; m < 64; m <<= 1){ s += __shfl_xor(s, m); sq += __shfl_xor(sq, m); }
  if (lane == 0){
    float mu  = s * (1.0f / DD);
    float var = sq * (1.0f / DD) - mu * mu;
    st[2*row]     = mu;
    st[2*row + 1] = 1.0f / sqrtf(var + 1e-5f);
  }
}

// ---------- LN apply + bf16(hi) convert (for fc1 A-plane) ----------
__global__ __launch_bounds__(256) void lncvt_kernel(const float* __restrict__ x,
    const float* __restrict__ st, const float* __restrict__ g,
    const float* __restrict__ b, us* __restrict__ out)
{
  int row = blockIdx.x, tid = threadIdx.x;
  float mu = st[2*row], rstd = st[2*row + 1];
  float4 xv = *(const float4*)(x + (size_t)row * DD + tid * 4);
  float4 gv = *(const float4*)(g + tid * 4);
  float4 bv = *(const float4*)(b + tid * 4);
  s4v o;
  o[0] = (short)f2bf((xv.x - mu) * rstd * gv.x + bv.x);
  o[1] = (short)f2bf((xv.y - mu) * rstd * gv.y + bv.y);
  o[2] = (short)f2bf((xv.z - mu) * rstd * gv.z + bv.z);
  o[3] = (short)f2bf((xv.w - mu) * rstd * gv.w + bv.w);
  *(s4v*)(out + (size_t)row * DD + tid * 4) = o;
}

// ------------- weight transpose + bf16 hi/lo split (optional g-fold) -------------
__global__ __launch_bounds__(256) void wt_kernel(const float* __restrict__ src,
                                                 us* __restrict__ dhi,
                                                 us* __restrict__ dlo,
                                                 const float* __restrict__ gscale,
                                                 int K, int N)
{
  __shared__ float t[32][33];
  int tx = threadIdx.x, ty = threadIdx.y;
  int n0 = blockIdx.x * 32, k0 = blockIdx.y * 32;
  #pragma unroll
  for (int r = 0; r < 4; r++)
    t[ty + 8*r][tx] = src[(size_t)(k0 + ty + 8*r) * N + n0 + tx];
  __syncthreads();
  float gs = gscale ? gscale[k0 + tx] : 1.0f;
  #pragma unroll
  for (int r = 0; r < 4; r++){
    float f = t[tx][ty + 8*r] * gs;
    us hi = f2bf(f);
    size_t o = (size_t)(n0 + ty + 8*r) * K + k0 + tx;
    dhi[o] = hi;
    if (dlo) dlo[o] = f2bf(f - bf2f(hi));
  }
}

// ---- column sums: c1[n] = sum_k g_k W_kn, c2[n] = sum_k b_k W_kn (stacked QKV) ----
__global__ __launch_bounds__(256) void qc_kernel(const float* __restrict__ Wq,
    const float* __restrict__ Wk, const float* __restrict__ Wv,
    const float* __restrict__ g, const float* __restrict__ b,
    float* __restrict__ c1, float* __restrict__ c2)
{
  __shared__ float p1[4][64], p2[4][64];
  int n0 = blockIdx.x * 64;                 // 48 blocks over [0,3072)
  int kind = n0 >> 10, col0 = n0 & 1023;
  const float* W = (kind == 0) ? Wq : (kind == 1) ? Wk : Wv;
  int tx = threadIdx.x & 63, ty = threadIdx.x >> 6;
  float s1 = 0.0f, s2 = 0.0f;
  for (int k = ty; k < 1024; k += 4){
    float w = W[(size_t)k * 1024 + col0 + tx];
    s1 += g[k] * w;
    s2 += b[k] * w;
  }
  p1[ty][tx] = s1; p2[ty][tx] = s2;
  __syncthreads();
  if (ty == 0){
    c1[n0 + tx] = p1[0][tx] + p1[1][tx] + p1[2][tx] + p1[3][tx];
    c2[n0 + tx] = p2[0][tx] + p2[1][tx] + p2[2][tx] + p2[3][tx];
  }
}

// -------- fused QKV GEMM, LN folded into weights, 128x256 tile, 512 threads --------
__global__ __launch_bounds__(512) void qkv_kernel(const float* __restrict__ hidden,
    const us* __restrict__ WBh, const us* __restrict__ WBl,
    const float* __restrict__ bq, const float* __restrict__ bk, const float* __restrict__ bv,
    const float* __restrict__ lnstat, const float* __restrict__ c1, const float* __restrict__ c2,
    us* __restrict__ qhp, us* __restrict__ qlp, us* __restrict__ khp,
    us* __restrict__ klp, us* __restrict__ vhp, us* __restrict__ vlp)
{
  const int M = M1, K = DD;
  __shared__ __align__(16) us Ah[128*40];   // padded stride 40 u16 (2-way-free reads)
  __shared__ __align__(16) us Al[128*40];
  __shared__ __align__(16) us Bh[256*32];   // linear (gload_lds dest), src-XOR swizzled
  __shared__ __align__(16) us Bl[256*32];
  int tid = threadIdx.x;
  int m0 = blockIdx.y * 128, n0 = blockIdx.x * 256;
  int lane = tid & 63, w = tid >> 6;        // 8 waves
  int wr = w >> 2, wc = w & 3;              // 2 (M) x 4 (N)
  int fr = lane & 15, fq = lane >> 4;
  f4v acc[4][4];
  f4v zero = {0.0f, 0.0f, 0.0f, 0.0f};
  #pragma unroll
  for (int i = 0; i < 4; i++)
    #pragma unroll
    for (int j = 0; j < 4; j++) acc[i][j] = zero;
  int sr = tid >> 2, sc4 = (tid & 3) * 8;
  int ar = m0 + sr; if (ar >= M) ar = M - 1;
  int lr = lane >> 2, lc = (lane & 3) * 8;
  int gb0 = n0 + w*32 + lr;
  int swl = ((lr >> 1) & 3) << 3;
  int swr = ((fr >> 1) & 3) << 3;

  for (int kk = 0; kk < K; kk += 32){
    {
      const float* ap = hidden + (size_t)ar * K + kk + sc4;
      float4 fa = *(const float4*)(ap);
      float4 fb = *(const float4*)(ap + 4);
      unsigned h0, h1, h2, h3, l0, l1, l2, l3;
      splitpk(fa.x, fa.y, h0, l0);
      splitpk(fa.z, fa.w, h1, l1);
      splitpk(fb.x, fb.y, h2, l2);
      splitpk(fb.z, fb.w, h3, l3);
      uint4 hv = {h0, h1, h2, h3};
      uint4 lv = {l0, l1, l2, l3};
      *(uint4*)&Ah[sr*40 + sc4] = hv;
      *(uint4*)&Al[sr*40 + sc4] = lv;
    }
    gl16(WBh + (size_t)gb0 * K + kk + (lc ^ swl),        &Bh[(w*32)*32]);
    gl16(WBh + (size_t)(gb0 + 16) * K + kk + (lc ^ swl), &Bh[(w*32 + 16)*32]);
    gl16(WBl + (size_t)gb0 * K + kk + (lc ^ swl),        &Bl[(w*32)*32]);
    gl16(WBl + (size_t)(gb0 + 16) * K + kk + (lc ^ swl), &Bl[(w*32 + 16)*32]);
    __syncthreads();
    s8v ah[4], bh[4], al[4], bl[4];
    #pragma unroll
    for (int m = 0; m < 4; m++){
      ah[m] = *(const s8v*)&Ah[(wr*64 + m*16 + fr)*40 + fq*8];
      al[m] = *(const s8v*)&Al[(wr*64 + m*16 + fr)*40 + fq*8];
    }
    #pragma unroll
    for (int n = 0; n < 4; n++){
      bh[n] = *(const s8v*)&Bh[(wc*64 + n*16 + fr)*32 + (fq*8 ^ swr)];
      bl[n] = *(const s8v*)&Bl[(wc*64 + n*16 + fr)*32 + (fq*8 ^ swr)];
    }
    #pragma unroll
    for (int m = 0; m < 4; m++)
      #pragma unroll
      for (int n = 0; n < 4; n++){
        acc[m][n] = __builtin_amdgcn_mfma_f32_16x16x32_bf16(ah[m], bh[n], acc[m][n], 0, 0, 0);
        acc[m][n] = __builtin_amdgcn_mfma_f32_16x16x32_bf16(ah[m], bl[n], acc[m][n], 0, 0, 0);
        acc[m][n] = __builtin_amdgcn_mfma_f32_16x16x32_bf16(al[m], bh[n], acc[m][n], 0, 0, 0);
      }
    __syncthreads();
  }
  int kind = n0 >> 10;
  const float* bsel = (kind == 0) ? bq : (kind == 1) ? bk : bv;
  us* O0 = (kind == 0) ? qhp : (kind == 1) ? khp : vhp;
  us* O1 = (kind == 0) ? qlp : (kind == 1) ? klp : vlp;
  float scl = (kind == 0) ? 0.125f : 1.0f;
  float C1r[4], C2r[4];
  int h2r[4], d2r[4];
  #pragma unroll
  for (int n = 0; n < 4; n++){
    int gcol = n0 + wc*64 + n*16 + fr;
    int lcn = gcol & 1023;
    h2r[n] = lcn >> 6; d2r[n] = lcn & 63;
    C1r[n] = c1[gcol];
    C2r[n] = c2[gcol] + bsel[lcn];
  }
  #pragma unroll
  for (int m = 0; m < 4; m++){
    int grow0 = m0 + wr*64 + m*16 + fq*4;
    #pragma unroll
    for (int i = 0; i < 4; i++){
      int grow = grow0 + i;
      if (grow < M){
        float mu = lnstat[2*grow], rstd = lnstat[2*grow + 1];
        int b2 = grow / 257, t2 = grow - b2 * 257;
        size_t rb = ((size_t)(b2*16) * 257 + t2) * 64;
        #pragma unroll
        for (int n = 0; n < 4; n++){
          size_t off2 = rb + (size_t)h2r[n] * (257*64) + d2r[n];
          float v = (rstd * acc[m][n][i] - rstd * mu * C1r[n] + C2r[n]) * scl;
          us hi = f2bf(v);
          O0[off2] = hi;
          O1[off2] = f2bf(v - bf2f(hi));
        }
      }
    }
  }
}

// -------- Wo GEMM: 256x256 tile, 512 threads, split-bf16, head-major gather A --------
// Halves both A-replay (8->4 N-blocks) and B-replay (129->65 M-blocks): Wo is FETCH-bound.
// Output: x = acc + bias + resid as hi/lo bf16 planes.
__global__ __launch_bounds__(512) void wo256_kernel(const us* __restrict__ Ahp,
    const us* __restrict__ Alp, const us* __restrict__ BTh, const us* __restrict__ BTl,
    const float* __restrict__ bias, const float* __restrict__ resid,
    us* __restrict__ C0, us* __restrict__ C1, int M, int N, int K)
{
  __shared__ __align__(16) us Ah[256*32];   // 16KB
  __shared__ __align__(16) us Al[256*32];
  __shared__ __align__(16) us Bh[256*32];
  __shared__ __align__(16) us Bl[256*32];   // 64KB total
  int tid = threadIdx.x;
  int m0 = blockIdx.y * 256, n0 = blockIdx.x * 256;
  int lane = tid & 63, w = tid >> 6;        // 8 waves
  int wr = w >> 2, wc = w & 3;              // wave tile 128(M) x 64(N)
  int fr = lane & 15, fq = lane >> 4;
  f4v acc[8][4];
  f4v zero = {0.0f, 0.0f, 0.0f, 0.0f};
  #pragma unroll
  for (int i = 0; i < 8; i++)
    #pragma unroll
    for (int j = 0; j < 4; j++) acc[i][j] = zero;
  int srow = w*16 + (lane >> 2);            // 0..127
  int lc = (lane & 3) * 8;
  int o16 = lc ^ (((srow >> 1) & 3) << 3);  // src-side XOR (rows srow and srow+128: same key)
  int swr = ((fr >> 1) & 3) << 3;
  int aR0 = m0 + srow;        if (aR0 >= M) aR0 = M - 1;
  int aR1 = m0 + 128 + srow;  if (aR1 >= M) aR1 = M - 1;
  int bR0 = n0 + srow;
  int bR1 = n0 + 128 + srow;
  int b2a = aR0 / 257, t2a = aR0 - b2a * 257;
  int b2b = aR1 / 257, t2b = aR1 - b2b * 257;

  for (int kk = 0; kk < K; kk += 32){
    int h2 = kk >> 6, d2 = (kk & 63) + o16;
    size_t oa0 = ((size_t)(b2a*16 + h2) * 257 + t2a) * 64 + d2;
    size_t oa1 = ((size_t)(b2b*16 + h2) * 257 + t2b) * 64 + d2;
    gl16(Ahp + oa0, &Ah[srow*32]);
    gl16(Ahp + oa1, &Ah[(128 + srow)*32]);
    gl16(Alp + oa0, &Al[srow*32]);
    gl16(Alp + oa1, &Al[(128 + srow)*32]);
    gl16(BTh + (size_t)bR0 * K + kk + o16, &Bh[srow*32]);
    gl16(BTh + (size_t)bR1 * K + kk + o16, &Bh[(128 + srow)*32]);
    gl16(BTl + (size_t)bR0 * K + kk + o16, &Bl[srow*32]);
    gl16(BTl + (size_t)bR1 * K + kk + o16, &Bl[(128 + srow)*32]);
    __syncthreads();
    #pragma unroll
    for (int mh = 0; mh < 2; mh++){
      s8v a_h[4], a_l[4], b_h[4], b_l[4];
      #pragma unroll
      for (int mt = 0; mt < 4; mt++){
        int r = wr*128 + mh*64 + mt*16 + fr;
        a_h[mt] = *(const s8v*)&Ah[r*32 + (fq*8 ^ swr)];
        a_l[mt] = *(const s8v*)&Al[r*32 + (fq*8 ^ swr)];
      }
      #pragma unroll
      for (int nt = 0; nt < 4; nt++){
        int r = wc*64 + nt*16 + fr;
        b_h[nt] = *(const s8v*)&Bh[r*32 + (fq*8 ^ swr)];
        b_l[nt] = *(const s8v*)&Bl[r*32 + (fq*8 ^ swr)];
      }
      #pragma unroll
      for (int mt = 0; mt < 4; mt++)
        #pragma unroll
        for (int nt = 0; nt < 4; nt++){
          acc[mh*4 + mt][nt] = __builtin_amdgcn_mfma_f32_16x16x32_bf16(a_h[mt], b_h[nt], acc[mh*4 + mt][nt], 0, 0, 0);
          acc[mh*4 + mt][nt] = __builtin_amdgcn_mfma_f32_16x16x32_bf16(a_h[mt], b_l[nt], acc[mh*4 + mt][nt], 0, 0, 0);
          acc[mh*4 + mt][nt] = __builtin_amdgcn_mfma_f32_16x16x32_bf16(a_l[mt], b_h[nt], acc[mh*4 + mt][nt], 0, 0, 0);
        }
    }
    __syncthreads();
  }
  // epilogue: x = acc + bias + resid -> hi/lo planes
  #pragma unroll
  for (int mh = 0; mh < 2; mh++)
    #pragma unroll
    for (int mt = 0; mt < 4; mt++){
      int grow0 = m0 + wr*128 + mh*64 + mt*16 + fq*4;
      #pragma unroll
      for (int nt = 0; nt < 4; nt++){
        int gcol = n0 + wc*64 + nt*16 + fr;
        float bcol = bias[gcol];
        #pragma unroll
        for (int i = 0; i < 4; i++){
          int grow = grow0 + i;
          if (grow < M){
            size_t off = (size_t)grow * N + gcol;
            float x = acc[mh*4 + mt][nt][i] + bcol + resid[off];
            us h, l;
            split1(x, h, l);
            C0[off] = h;
            C1[off] = l;
          }
        }
      }
    }
}

// ------- 256x256 counted-vmcnt pipelined GEMM (fc1/fc2), plain bf16 -------
template<int EPI>
__global__ __launch_bounds__(512) void gemm8p_kernel(const us* __restrict__ A,
    const us* __restrict__ B, const float* __restrict__ bias,
    const float* __restrict__ resid, void* __restrict__ C, int M, int N, int K)
{
  __shared__ __align__(16) us As[3][256*32];   // 16KB each
  __shared__ __align__(16) us Bs[3][256*32];
  int tid = threadIdx.x;
  int m0 = blockIdx.y * 256, n0 = blockIdx.x * 256;
  int lane = tid & 63, w = tid >> 6;           // 8 waves
  int wr = w >> 2, wc = w & 3;                 // wave tile 128x64
  int fr = lane & 15, fq = lane >> 4;
  f4v acc[8][4];
  f4v zero = {0.0f, 0.0f, 0.0f, 0.0f};
  #pragma unroll
  for (int i = 0; i < 8; i++)
    #pragma unroll
    for (int j = 0; j < 4; j++) acc[i][j] = zero;
  int srow = w*16 + (lane >> 2);
  int aR0 = m0 + srow;        if (aR0 >= M) aR0 = M - 1;
  int aR1 = m0 + 128 + srow;  if (aR1 >= M) aR1 = M - 1;
  int bR0 = n0 + srow;
  int bR1 = n0 + 128 + srow;
  int o16 = ((lane & 3) * 8) ^ (((srow >> 1) & 3) << 3);   // 16B-granule src XOR
  int swr = ((fr >> 1) & 3) << 3;
  int ldst = w * 512;                                      // u16, + r*4096

  const int NT = K >> 5;
  #pragma unroll
  for (int t0 = 0; t0 < 2; t0++){
    gl16(A + (size_t)aR0 * K + t0*32 + o16, &As[t0][ldst]);
    gl16(B + (size_t)bR0 * K + t0*32 + o16, &Bs[t0][ldst]);
    gl16(A + (size_t)aR1 * K + t0*32 + o16, &As[t0][4096 + ldst]);
    gl16(B + (size_t)bR1 * K + t0*32 + o16, &Bs[t0][4096 + ldst]);
  }
  asm volatile("s_waitcnt vmcnt(4)" ::: "memory");
  __builtin_amdgcn_s_barrier();

  int buf = 0;
  #pragma unroll 1
  for (int t = 0; t < NT; ++t){
    int nbuf = buf + 2; if (nbuf >= 3) nbuf -= 3;
    bool pf = (t + 2) < NT;
    int kk2 = (t + 2) * 32;
    us* Ab = As[buf];
    us* Bb = Bs[buf];
    {
      s8v a[4], b[4];
      #pragma unroll
      for (int mt = 0; mt < 4; mt++){
        int r = wr*128 + mt*16 + fr;
        a[mt] = *(const s8v*)&Ab[r*32 + (fq*8 ^ swr)];
      }
      #pragma unroll
      for (int nt = 0; nt < 4; nt++){
        int r = wc*64 + nt*16 + fr;
        b[nt] = *(const s8v*)&Bb[r*32 + (fq*8 ^ swr)];
      }
      if (pf){
        gl16(A + (size_t)aR0 * K + kk2 + o16, &As[nbuf][ldst]);
        gl16(B + (size_t)bR0 * K + kk2 + o16, &Bs[nbuf][ldst]);
      }
      __builtin_amdgcn_s_barrier();
      __builtin_amdgcn_s_setprio(1);
      #pragma unroll
      for (int mt = 0; mt < 4; mt++)
        #pragma unroll
        for (int nt = 0; nt < 4; nt++)
          acc[mt][nt] = __builtin_amdgcn_mfma_f32_16x16x32_bf16(a[mt], b[nt], acc[mt][nt], 0, 0, 0);
      __builtin_amdgcn_s_setprio(0);
      __builtin_amdgcn_s_barrier();
    }
    {
      s8v a[4], b[4];
      #pragma unroll
      for (int mt = 0; mt < 4; mt++){
        int r = wr*128 + 64 + mt*16 + fr;
        a[mt] = *(const s8v*)&Ab[r*32 + (fq*8 ^ swr)];
      }
      #pragma unroll
      for (int nt = 0; nt < 4; nt++){
        int r = wc*64 + nt*16 + fr;
        b[nt] = *(const s8v*)&Bb[r*32 + (fq*8 ^ swr)];
      }
      if (pf){
        gl16(A + (size_t)aR1 * K + kk2 + o16, &As[nbuf][4096 + ldst]);
        gl16(B + (size_t)bR1 * K + kk2 + o16, &Bs[nbuf][4096 + ldst]);
      }
      __builtin_amdgcn_s_barrier();
      __builtin_amdgcn_s_setprio(1);
      #pragma unroll
      for (int mt = 0; mt < 4; mt++)
        #pragma unroll
        for (int nt = 0; nt < 4; nt++)
          acc[4 + mt][nt] = __builtin_amdgcn_mfma_f32_16x16x32_bf16(a[mt], b[nt], acc[4 + mt][nt], 0, 0, 0);
      __builtin_amdgcn_s_setprio(0);
    }
    if (t + 1 < NT){
      if (pf) asm volatile("s_waitcnt vmcnt(4)" ::: "memory");
      else    asm volatile("s_waitcnt vmcnt(0)" ::: "memory");
    }
    __builtin_amdgcn_s_barrier();
    buf = buf + 1; if (buf >= 3) buf = 0;
  }
  #pragma unroll
  for (int mh = 0; mh < 2; mh++)
    #pragma unroll
    for (int mt = 0; mt < 4; mt++){
      int grow0 = m0 + wr*128 + mh*64 + mt*16 + fq*4;
      #pragma unroll
      for (int nt = 0; nt < 4; nt++){
        int gcol = n0 + wc*64 + nt*16 + fr;
        float bcol = bias[gcol];
        #pragma unroll
        for (int i = 0; i < 4; i++){
          int grow = grow0 + i;
          if (grow < M){
            float v = acc[mh*4 + mt][nt][i] + bcol;
            size_t off = (size_t)grow * N + gcol;
            if (EPI == 1){
              ((float*)C)[off] = v + resid[off];
            } else {
              float gq = v / (1.0f + expf(-1.702f * v));
              ((us*)C)[off] = f2bf(gq);
            }
          }
        }
      }
    }
}

// ------- flash MFMA split-bf16 attention, head-major planes; O aliases Q -------
__global__ __launch_bounds__(512, 1) void attn_flash_kernel(
    const us* __restrict__ Qh, const us* __restrict__ Ql,
    const us* __restrict__ Kh, const us* __restrict__ Klo,
    const us* __restrict__ Vh, const us* __restrict__ Vlo,
    us* Oh, us* Ol)
{
  __shared__ __align__(16) us Kl[257 * 128];  // 65,792 B
  __shared__ __align__(16) us Vl[64 * 640];   // 81,920 B
  int bh = blockIdx.x;
  const size_t hb = (size_t)bh * 257 * 64;
  int tid = threadIdx.x;
  int l = tid & 63, w = tid >> 6;  // w in 0..7
  int g = l >> 4, c = l & 15;
  const float NEG = -3.0e38f;

  {
    s8v z8 = {0,0,0,0,0,0,0,0};
    for (int idx = tid; idx < 64*640/8; idx += 512)
      *((s8v*)Vl + idx) = z8;
  }
  __syncthreads();
  for (int idx = tid; idx < 257*8; idx += 512){
    int tok = idx >> 3, ch = idx & 7;
    int sw = (tok & 7) << 4;
    s8v hv = *(const s8v*)(Kh  + hb + (size_t)tok * 64 + ch*8);
    s8v lv = *(const s8v*)(Klo + hb + (size_t)tok * 64 + ch*8);
    char* kr = (char*)Kl + tok * 256;
    *(s8v*)(kr + ((ch*16) ^ sw)) = hv;
    *(s8v*)(kr + 128 + ((ch*16) ^ sw)) = lv;
  }
  for (int idx = tid; idx < 257*8; idx += 512){
    int tok = idx >> 3, ch = idx & 7;
    s8v hv = *(const s8v*)(Vh  + hb + (size_t)tok * 64 + ch*8);
    s8v lv = *(const s8v*)(Vlo + hb + (size_t)tok * 64 + ch*8);
    #pragma unroll
    for (int j = 0; j < 8; j++){
      int d = ch*8 + j;
      char* vr = (char*)Vl + d * 1280;
      int off = (tok * 2) ^ (j << 4);
      *(us*)(vr + off) = (us)hv[j];
      *(us*)(vr + 640 + off) = (us)lv[j];
    }
  }
  __syncthreads();

  for (int qt = w; qt < 17; qt += 8){
    int t0 = qt * 16;
    int qr = t0 + c; if (qr > 256) qr = 256;
    const us* qp  = Qh + hb + (size_t)qr * 64 + g*8;
    const us* qp2 = Ql + hb + (size_t)qr * 64 + g*8;
    s8v qhi[2], qlo[2];
    qhi[0] = *(const s8v*)(qp);       qhi[1] = *(const s8v*)(qp + 32);
    qlo[0] = *(const s8v*)(qp2);      qlo[1] = *(const s8v*)(qp2 + 32);

    float m_run = NEG, l_run = 0.0f;
    f4v o4[4];
    #pragma unroll
    for (int dt = 0; dt < 4; dt++) o4[dt] = (f4v){0.0f, 0.0f, 0.0f, 0.0f};

    #pragma unroll 1
    for (int mck = 0; mck < 9; mck++){
      f4v a0, a1;
      {
        int t = 2*mck;
        int krow = t * 16 + c; if (krow > 256) krow = 256;
        char* kr = (char*)Kl + krow * 256;
        int sw = (krow & 7) << 4;
        s8v khi0 = *(const s8v*)(kr + ((g * 16) ^ sw));
        s8v khi1 = *(const s8v*)(kr + ((64 + g * 16) ^ sw));
        s8v klo0 = *(const s8v*)(kr + 128 + ((g * 16) ^ sw));
        s8v klo1 = *(const s8v*)(kr + 128 + ((64 + g * 16) ^ sw));
        f4v a = {0.0f, 0.0f, 0.0f, 0.0f};
        a = __builtin_amdgcn_mfma_f32_16x16x32_bf16(khi0, qhi[0], a, 0, 0, 0);
        a = __builtin_amdgcn_mfma_f32_16x16x32_bf16(khi1, qhi[1], a, 0, 0, 0);
        a = __builtin_amdgcn_mfma_f32_16x16x32_bf16(khi0, qlo[0], a, 0, 0, 0);
        a = __builtin_amdgcn_mfma_f32_16x16x32_bf16(khi1, qlo[1], a, 0, 0, 0);
        a = __builtin_amdgcn_mfma_f32_16x16x32_bf16(klo0, qhi[0], a, 0, 0, 0);
        a = __builtin_amdgcn_mfma_f32_16x16x32_bf16(klo1, qhi[1], a, 0, 0, 0);
        a0 = a;
      }
      if (mck < 8){
        int t = 2*mck + 1;
        int krow = t * 16 + c; if (krow > 256) krow = 256;
        char* kr = (char*)Kl + krow * 256;
        int sw = (krow & 7) << 4;
        s8v khi0 = *(const s8v*)(kr + ((g * 16) ^ sw));
        s8v khi1 = *(const s8v*)(kr + ((64 + g * 16) ^ sw));
        s8v klo0 = *(const s8v*)(kr + 128 + ((g * 16) ^ sw));
        s8v klo1 = *(const s8v*)(kr + 128 + ((64 + g * 16) ^ sw));
        f4v a = {0.0f, 0.0f, 0.0f, 0.0f};
        a = __builtin_amdgcn_mfma_f32_16x16x32_bf16(khi0, qhi[0], a, 0, 0, 0);
        a = __builtin_amdgcn_mfma_f32_16x16x32_bf16(khi1, qhi[1], a, 0, 0, 0);
        a = __builtin_amdgcn_mfma_f32_16x16x32_bf16(khi0, qlo[0], a, 0, 0, 0);
        a = __builtin_amdgcn_mfma_f32_16x16x32_bf16(khi1, qlo[1], a, 0, 0, 0);
        a = __builtin_amdgcn_mfma_f32_16x16x32_bf16(klo0, qhi[0], a, 0, 0, 0);
        a = __builtin_amdgcn_mfma_f32_16x16x32_bf16(klo1, qhi[1], a, 0, 0, 0);
        a1 = a;
      } else {
        a1 = (f4v){NEG, NEG, NEG, NEG};
        a0[0] = (g == 0) ? a0[0] : NEG;
        a0[1] = NEG; a0[2] = NEG; a0[3] = NEG;
      }
      float cm = fmaxf(fmaxf(fmaxf(a0[0], a0[1]), fmaxf(a0[2], a0[3])),
                       fmaxf(fmaxf(a1[0], a1[1]), fmaxf(a1[2], a1[3])));
      cm = fmaxf(cm, __shfl_xor(cm, 16));
      cm = fmaxf(cm, __shfl_xor(cm, 32));
      float m_new = fmaxf(m_run, cm);
      float scl = __expf(m_run - m_new);
      m_run = m_new;
      l_run *= scl;
      #pragma unroll
      for (int dt = 0; dt < 4; dt++){
        o4[dt][0] *= scl; o4[dt][1] *= scl; o4[dt][2] *= scl; o4[dt][3] *= scl;
      }
      float ls = 0.0f;
      unsigned Ph2[2][2], Pl2[2][2];
      #pragma unroll
      for (int k2 = 0; k2 < 2; k2++){
        float e0 = __expf(a0[2*k2] - m_new), e1 = __expf(a0[2*k2+1] - m_new);
        ls += e0 + e1;
        us h0 = f2bf(e0), h1 = f2bf(e1);
        Ph2[0][k2] = (unsigned)h0 | ((unsigned)h1 << 16);
        Pl2[0][k2] = (unsigned)f2bf(e0 - bf2f(h0)) | ((unsigned)f2bf(e1 - bf2f(h1)) << 16);
        float e2 = __expf(a1[2*k2] - m_new), e3 = __expf(a1[2*k2+1] - m_new);
        ls += e2 + e3;
        us h2 = f2bf(e2), h3 = f2bf(e3);
        Ph2[1][k2] = (unsigned)h2 | ((unsigned)h3 << 16);
        Pl2[1][k2] = (unsigned)f2bf(e2 - bf2f(h2)) | ((unsigned)f2bf(e3 - bf2f(h3)) << 16);
      }
      l_run += ls;
      s8v pbh, pbl;
      #pragma unroll
      for (int ww = 0; ww < 4; ww++){
        int srcl = (((g & 1) * 2 + (ww >> 1)) << 4) | c;
        unsigned h0 = (unsigned)__shfl((int)Ph2[0][ww & 1], srcl, 64);
        unsigned lo0 = (unsigned)__shfl((int)Pl2[0][ww & 1], srcl, 64);
        unsigned h1 = (unsigned)__shfl((int)Ph2[1][ww & 1], srcl, 64);
        unsigned lo1 = (unsigned)__shfl((int)Pl2[1][ww & 1], srcl, 64);
        ((unsigned*)&pbh)[ww] = (g >> 1) ? h1 : h0;
        ((unsigned*)&pbl)[ww] = (g >> 1) ? lo1 : lo0;
      }
      #pragma unroll
      for (int dt = 0; dt < 4; dt++){
        int d = dt * 16 + c;
        char* vr = (char*)Vl + d * 1280;
        int off = (mck * 64 + g * 16) ^ ((d & 7) << 4);
        s8v vh = *(const s8v*)(vr + off);
        s8v vlo = *(const s8v*)(vr + 640 + off);
        o4[dt] = __builtin_amdgcn_mfma_f32_16x16x32_bf16(vh, pbh, o4[dt], 0, 0, 0);
        o4[dt] = __builtin_amdgcn_mfma_f32_16x16x32_bf16(vh, pbl, o4[dt], 0, 0, 0);
        o4[dt] = __builtin_amdgcn_mfma_f32_16x16x32_bf16(vlo, pbh, o4[dt], 0, 0, 0);
      }
    }
    l_run += __shfl_xor(l_run, 16);
    l_run += __shfl_xor(l_run, 32);
    float inv = 1.0f / l_run;
    int qrow = t0 + c;
    if (qrow <= 256){
      us* oph = Oh + hb + (size_t)qrow * 64;
      us* opl = Ol + hb + (size_t)qrow * 64;
      #pragma unroll
      for (int dt = 0; dt < 4; dt++){
        s4v hv4, lv4;
        #pragma unroll
        for (int i = 0; i < 4; i++){
          float ov = o4[dt][i] * inv;
          us hi = f2bf(ov);
          hv4[i] = (short)hi;
          lv4[i] = (short)f2bf(ov - bf2f(hi));
        }
        *(s4v*)(oph + dt*16 + g*4) = hv4;
        *(s4v*)(opl + dt*16 + g*4) = lv4;
      }
    }
  }
}

// ---------------- row norms from hi/lo planes ----------------
__global__ __launch_bounds__(64) void norms_kernel(const us* __restrict__ xh,
    const us* __restrict__ xl, float* __restrict__ nrm)
{
  int row = blockIdx.x, lane = threadIdx.x;
  const us* ph = xh + (size_t)row * DD + lane * 16;
  const us* pl = xl + (size_t)row * DD + lane * 16;
  float sq = 0.0f;
  #pragma unroll
  for (int i = 0; i < 2; i++){
    s8v h = *(const s8v*)(ph + i * 8);
    s8v l = *(const s8v*)(pl + i * 8);
    #pragma unroll
    for (int j = 0; j < 8; j++){
      float v = bf2f((us)h[j]) + bf2f((us)l[j]);
      sq += v * v;
    }
  }
  #pragma unroll
  for (int m = 1; m < 64; m <<= 1) sq += __shfl_xor(sq, m);
  if (lane == 0) nrm[row] = sqrtf(sq);
}

// ------- cosine scores via split-bf16 MFMA (even x odd tokens) -------
__global__ __launch_bounds__(256) void scores8_kernel(const us* __restrict__ xh,
    const us* __restrict__ xl, const float* __restrict__ nrm, float* __restrict__ sc)
{
  __shared__ __align__(16) us Ah[128*32];
  __shared__ __align__(16) us Al[128*32];
  __shared__ __align__(16) us Bh[128*32];
  __shared__ __align__(16) us Bl[128*32];
  int mblk = blockIdx.x, b = blockIdx.y;
  const size_t rb = (size_t)b * TT * DD;
  int tid = threadIdx.x;
  int lane = tid & 63, w = tid >> 6;
  int wr = w >> 1, wc = w & 1;
  int fr = lane & 15, fq = lane >> 4;
  f4v acc[4][4];
  f4v zero = {0.0f, 0.0f, 0.0f, 0.0f};
  #pragma unroll
  for (int i = 0; i < 4; i++)
    #pragma unroll
    for (int j = 0; j < 4; j++) acc[i][j] = zero;
  int lr = lane >> 2, lc = (lane & 3) * 8;
  int swl = ((lr >> 1) & 3) << 3;
  int swr = ((fr >> 1) & 3) << 3;
  int ra0 = mblk*128 + w*32 + lr;      if (ra0 > 128) ra0 = 128;
  int ra1 = mblk*128 + w*32 + 16 + lr; if (ra1 > 128) ra1 = 128;
  size_t ta0 = (size_t)(2 * ra0) * DD, ta1 = (size_t)(2 * ra1) * DD;
  size_t tb0 = (size_t)(2 * (w*32 + lr) + 1) * DD;
  size_t tb1 = (size_t)(2 * (w*32 + 16 + lr) + 1) * DD;

  for (int kk = 0; kk < DD; kk += 32){
    int co = kk + (lc ^ swl);
    gl16(xh + rb + ta0 + co, &Ah[(w*32)*32]);
    gl16(xh + rb + ta1 + co, &Ah[(w*32 + 16)*32]);
    gl16(xl + rb + ta0 + co, &Al[(w*32)*32]);
    gl16(xl + rb + ta1 + co, &Al[(w*32 + 16)*32]);
    gl16(xh + rb + tb0 + co, &Bh[(w*32)*32]);
    gl16(xh + rb + tb1 + co, &Bh[(w*32 + 16)*32]);
    gl16(xl + rb + tb0 + co, &Bl[(w*32)*32]);
    gl16(xl + rb + tb1 + co, &Bl[(w*32 + 16)*32]);
    __syncthreads();
    s8v ah[4], bh[4], al[4], bl[4];
    #pragma unroll
    for (int m = 0; m < 4; m++){
      ah[m] = *(const s8v*)&Ah[(wr*64 + m*16 + fr)*32 + (fq*8 ^ swr)];
      al[m] = *(const s8v*)&Al[(wr*64 + m*16 + fr)*32 + (fq*8 ^ swr)];
    }
    #pragma unroll
    for (int n = 0; n < 4; n++){
      bh[n] = *(const s8v*)&Bh[(wc*64 + n*16 + fr)*32 + (fq*8 ^ swr)];
      bl[n] = *(const s8v*)&Bl[(wc*64 + n*16 + fr)*32 + (fq*8 ^ swr)];
    }
    #pragma unroll
    for (int m = 0; m < 4; m++)
      #pragma unroll
      for (int n = 0; n < 4; n++){
        acc[m][n] = __builtin_amdgcn_mfma_f32_16x16x32_bf16(ah[m], bh[n], acc[m][n], 0, 0, 0);
        acc[m][n] = __builtin_amdgcn_mfma_f32_16x16x32_bf16(ah[m], bl[n], acc[m][n], 0, 0, 0);
        acc[m][n] = __builtin_amdgcn_mfma_f32_16x16x32_bf16(al[m], bh[n], acc[m][n], 0, 0, 0);
      }
    __syncthreads();
  }
  #pragma unroll
  for (int m = 0; m < 4; m++){
    int grow0 = mblk*128 + wr*64 + m*16 + fq*4;
    #pragma unroll
    for (int n = 0; n < 4; n++){
      int gcol = wc*64 + n*16 + fr;
      float no = nrm[(size_t)b * TT + 2*gcol + 1];
      #pragma unroll
      for (int i = 0; i < 4; i++){
        int grow = grow0 + i;
        if (grow < NA){
          float ne = nrm[(size_t)b * TT + 2*grow];
          sc[((size_t)b * NA + grow) * NB + gcol] = acc[m][n][i] / (ne * no);
        }
      }
    }
  }
}

// ---------------- per-row max/argmax (first occurrence) ----------------
__global__ __launch_bounds__(64) void node_kernel(const float* __restrict__ sc,
                                                  float* __restrict__ nmax, int* __restrict__ nidx)
{
  int i = blockIdx.x, b = blockIdx.y, lane = threadIdx.x;
  const float* row = sc + ((size_t)b * NA + i) * NB;
  float v0 = row[lane];
  float v1 = row[lane + 64];
  float bv = v0; int bi = lane;
  if (v1 > bv){ bv = v1; bi = lane + 64; }
  #pragma unroll
  for (int m = 1; m < 64; m <<= 1){
    float ov = __shfl_xor(bv, m);
    int oi = __shfl_xor(bi, m);
    if (ov > bv || (ov == bv && oi < bi)){ bv = ov; bi = oi; }
  }
  if (lane == 0){
    if (i == 0){ nmax[(size_t)b * NA] = -INFINITY; nidx[(size_t)b * NA] = 0; }
    else { nmax[(size_t)b * NA + i] = bv; nidx[(size_t)b * NA + i] = bi; }
  }
}

// ------------- stable descending argsort + select -------------
__global__ __launch_bounds__(256) void rank_kernel(const float* __restrict__ nmax,
    const int* __restrict__ nidx, int* __restrict__ src, int* __restrict__ dst,
    int* __restrict__ unm, int* __restrict__ cnt)
{
  __shared__ float v[NA];
  __shared__ int rk[NA];
  __shared__ int edge[NA];
  __shared__ int cs[NB];
  int b = blockIdx.x, t = threadIdx.x;
  if (t < NA) v[t] = nmax[(size_t)b * NA + t];
  if (t < NB) cs[t] = 0;
  __syncthreads();
  if (t < NA){
    float vt = v[t]; int r = 0;
    for (int i = 0; i < NA; i++){
      float vi = v[i];
      r += (vi > vt) || (vi == vt && i < t);
    }
    rk[t] = r; edge[r] = t;
  }
  __syncthreads();
  if (t < RR){
    int s = edge[t];
    src[b * RR + t] = s;
    int d = nidx[(size_t)b * NA + s];
    dst[b * RR + t] = d;
    atomicAdd(&cs[d], 1);
  }
  if (t < NA && rk[t] >= RR){
    int p = 0;
    for (int i = 0; i < NA; i++) p += (i < t) && (rk[i] >= RR);
    unm[b * (NA - RR) + p] = t;
  }
  __syncthreads();
  if (t < NB) cnt[b * NB + t] = cs[t];
}

// ---------------- merge (reads hi/lo planes) ----------------
__global__ __launch_bounds__(256) void merge_kernel(const us* __restrict__ xh,
    const us* __restrict__ xl,
    const int* __restrict__ src, const int* __restrict__ dst, const int* __restrict__ unm,
    const int* __restrict__ cnt, float* __restrict__ xm)
{
  int u = blockIdx.x, b = blockIdx.y;
  int c = threadIdx.x * 4;
  const us* xhb = xh + (size_t)b * TT * DD;
  const us* xlb = xl + (size_t)b * TT * DD;
  float4 acc;
  if (u < NA - RR){
    int ts = 2 * unm[b * (NA - RR) + u];
    s4v h = *(const s4v*)(xhb + (size_t)ts * DD + c);
    s4v l = *(const s4v*)(xlb + (size_t)ts * DD + c);
    acc.x = bf2f((us)h[0]) + bf2f((us)l[0]);
    acc.y = bf2f((us)h[1]) + bf2f((us)l[1]);
    acc.z = bf2f((us)h[2]) + bf2f((us)l[2]);
    acc.w = bf2f((us)h[3]) + bf2f((us)l[3]);
  } else {
    int j = u - (NA - RR);
    s4v h = *(const s4v*)(xhb + (size_t)(2*j + 1) * DD + c);
    s4v l = *(const s4v*)(xlb + (size_t)(2*j + 1) * DD + c);
    acc.x = bf2f((us)h[0]) + bf2f((us)l[0]);
    acc.y = bf2f((us)h[1]) + bf2f((us)l[1]);
    acc.z = bf2f((us)h[2]) + bf2f((us)l[2]);
    acc.w = bf2f((us)h[3]) + bf2f((us)l[3]);
    #pragma unroll
    for (int k2 = 0; k2 < RR; k2++){
      if (dst[b * RR + k2] == j){
        int ts = 2 * src[b * RR + k2];
        s4v ah4 = *(const s4v*)(xhb + (size_t)ts * DD + c);
        s4v al4 = *(const s4v*)(xlb + (size_t)ts * DD + c);
        acc.x += bf2f((us)ah4[0]) + bf2f((us)al4[0]);
        acc.y += bf2f((us)ah4[1]) + bf2f((us)al4[1]);
        acc.z += bf2f((us)ah4[2]) + bf2f((us)al4[2]);
        acc.w += bf2f((us)ah4[3]) + bf2f((us)al4[3]);
      }
    }
    float inv = 1.0f / (float)(1 + cnt[b * NB + j]);
    acc.x *= inv; acc.y *= inv; acc.z *= inv; acc.w *= inv;
  }
  *(float4*)(xm + ((size_t)b * TMM + u) * DD + c) = acc;
}

// ---------------- launch ----------------
extern "C" void kernel_launch(void* const* d_in, const int* in_sizes, int n_in,
                              void* d_out, int out_size, void* d_ws, size_t ws_size,
                              hipStream_t stream)
{
  (void)in_sizes; (void)n_in; (void)out_size; (void)ws_size;
  const float* hidden = (const float*)d_in[0];
  const float* ln1_g  = (const float*)d_in[1];
  const float* ln1_b  = (const float*)d_in[2];
  const float* Wq = (const float*)d_in[3];
  const float* bq = (const float*)d_in[4];
  const float* Wk = (const float*)d_in[5];
  const float* bk = (const float*)d_in[6];
  const float* Wv = (const float*)d_in[7];
  const float* bv = (const float*)d_in[8];
  const float* Wo = (const float*)d_in[9];
  const float* bo = (const float*)d_in[10];
  const float* ln2_g = (const float*)d_in[11];
  const float* ln2_b = (const float*)d_in[12];
  const float* W1 = (const float*)d_in[13];
  const float* b1 = (const float*)d_in[14];
  const float* W2 = (const float*)d_in[15];
  const float* b2 = (const float*)d_in[16];

  char* base = (char*)d_ws;
  const size_t PE = (size_t)M1 * DD;          // plane elements
  const size_t PL = PE * sizeof(us);          // 33,685,504 B per plane
  us* qh = (us*)base;          us* ql = qh + PE;        // s0; attn O in-place
  us* kh = (us*)(base + 2*PL); us* kl = kh + PE;        // s1; later xbh/xbl planes
  us* vh = (us*)(base + 4*PL); us* vl = vh + PE;        // s2; later match scratch
  us* wts = (us*)(base + 6*PL);
  const size_t WD = (size_t)DD * DD;
  us* wqh = wts;
  us* wkh = wqh + WD;
  us* wvh = wkh + WD;
  us* wql = wvh + WD;
  us* wkl = wql + WD;
  us* wvl = wkl + WD;
  us* woh = wvl + WD;
  us* wol = woh + WD;
  us* w1h = wol + WD;
  us* w2h = w1h + (size_t)DD * FF;
  float* lnst1 = (float*)(w2h + (size_t)FF * DD);
  float* c1p   = lnst1 + 2 * M1;
  float* c2p   = c1p + 3072;                  // total 235,823,616 B
  us* xbh = (us*)(base + 2*PL);               // x = attn+resid as hi/lo planes (over kh/kl)
  us* xbl = xbh + PE;
  float* nrm   = (float*)(base + 4*PL);
  float* sc    = nrm + M1;
  float* nmaxp = sc + (size_t)BB * NA * NB;
  int*   nidxp = (int*)(nmaxp + BB * NA);
  int*   srcI  = nidxp + BB * NA;
  int*   dstI  = srcI + BB * RR;
  int*   unmI  = dstI + BB * RR;
  int*   cntI  = unmI + BB * (NA - RR);
  us*    xh2   = (us*)(base + 4*PL + (size_t)8*1024*1024);
  float* lnst2 = (float*)(base + 4*PL + (size_t)48*1024*1024);
  float* xm = (float*)d_out;
  us* mid = (us*)base;

  dim3 tb32(32, 8);
  wt_kernel<<<dim3(DD/32, DD/32), tb32, 0, stream>>>(Wq, wqh, wql, ln1_g, DD, DD);
  wt_kernel<<<dim3(DD/32, DD/32), tb32, 0, stream>>>(Wk, wkh, wkl, ln1_g, DD, DD);
  wt_kernel<<<dim3(DD/32, DD/32), tb32, 0, stream>>>(Wv, wvh, wvl, ln1_g, DD, DD);
  wt_kernel<<<dim3(DD/32, DD/32), tb32, 0, stream>>>(Wo, woh, wol, nullptr, DD, DD);
  wt_kernel<<<dim3(FF/32, DD/32), tb32, 0, stream>>>(W1, w1h, nullptr, nullptr, DD, FF);
  wt_kernel<<<dim3(DD/32, FF/32), tb32, 0, stream>>>(W2, w2h, nullptr, nullptr, FF, DD);

  qc_kernel<<<48, 256, 0, stream>>>(Wq, Wk, Wv, ln1_g, ln1_b, c1p, c2p);
  lnstats_kernel<<<M1, 64, 0, stream>>>(hidden, lnst1);

  qkv_kernel<<<dim3(3072/256, (M1 + 127)/128), 512, 0, stream>>>(hidden, wqh, wql,
      bq, bk, bv, lnst1, c1p, c2p, qh, ql, kh, kl, vh, vl);

  attn_flash_kernel<<<BB*HH, 512, 0, stream>>>(qh, ql, kh, kl, vh, vl, qh, ql);

  // Wo: 256x256 split GEMM over head-major O planes; x as hi/lo planes (over dead kh/kl)
  wo256_kernel<<<dim3(DD/256, (M1 + 255)/256), 512, 0, stream>>>(qh, ql, woh, wol,
      bo, hidden, xbh, xbl, M1, DD, DD);

  norms_kernel<<<M1, 64, 0, stream>>>(xbh, xbl, nrm);
  scores8_kernel<<<dim3(2, BB), 256, 0, stream>>>(xbh, xbl, nrm, sc);
  node_kernel<<<dim3(NA, BB), 64, 0, stream>>>(sc, nmaxp, nidxp);
  rank_kernel<<<BB, 256, 0, stream>>>(nmaxp, nidxp, srcI, dstI, unmI, cntI);
  merge_kernel<<<dim3(TMM, BB), 256, 0, stream>>>(xbh, xbl, srcI, dstI, unmI, cntI, xm);

  lnstats_kernel<<<M2, 64, 0, stream>>>(xm, lnst2);
  lncvt_kernel<<<M2, 256, 0, stream>>>(xm, lnst2, ln2_g, ln2_b, xh2);

  gemm8p_kernel<2><<<dim3(FF/256, (M2 + 255)/256), 512, 0, stream>>>(xh2, w1h,
      b1, nullptr, mid, M2, FF, DD);
  gemm8p_kernel<1><<<dim3(DD/256, (M2 + 255)/256), 512, 0, stream>>>(mid, w2h,
      b2, xm, (float*)d_out, M2, DD, FF);
}

// Round 21
// 1382.342 us; speedup vs baseline: 1.0419x; 1.0419x over previous
//
#include <hip/hip_runtime.h>
#include <math.h>

#define BB 64
#define TT 257
#define DD 1024
#define HH 16
#define FF 4096
#define RR 16
#define HDD 64
#define TMM 241          // T - R
#define M1 (BB*TT)       // 16448
#define M2 (BB*TMM)      // 15424
#define NA 129
#define NB 128

typedef float f4v __attribute__((ext_vector_type(4)));
typedef short s8v __attribute__((ext_vector_type(8)));
typedef short s4v __attribute__((ext_vector_type(4)));
typedef unsigned short us;

__device__ __forceinline__ us f2bf(float f){
  unsigned u = __float_as_uint(f);
  u += 0x7fffu + ((u >> 16) & 1u);
  return (us)(u >> 16);
}
__device__ __forceinline__ float bf2f(us h){
  return __uint_as_float(((unsigned)h) << 16);
}
// truncation hi/lo split of a pair, packed into u32 words (low=f0, high=f1)
__device__ __forceinline__ void splitpk(float f0, float f1, unsigned &hp, unsigned &lp){
  unsigned u0 = __float_as_uint(f0), u1 = __float_as_uint(f1);
  unsigned h0m = u0 & 0xFFFF0000u, h1m = u1 & 0xFFFF0000u;
  hp = (u0 >> 16) | h1m;
  float l0 = f0 - __uint_as_float(h0m);
  float l1 = f1 - __uint_as_float(h1m);
  lp = (__float_as_uint(l0) >> 16) | (__float_as_uint(l1) & 0xFFFF0000u);
}
// single-value truncation split
__device__ __forceinline__ void split1(float f, us &h, us &l){
  unsigned u = __float_as_uint(f);
  unsigned hm = u & 0xFFFF0000u;
  h = (us)(u >> 16);
  l = (us)(__float_as_uint(f - __uint_as_float(hm)) >> 16);
}
// async global->LDS, 16B per lane; LDS dest = wave-uniform base + lane*16, global src per-lane
__device__ __forceinline__ void gl16(const us* g, us* l){
  __builtin_amdgcn_global_load_lds((const __attribute__((address_space(1))) void*)g,
                                   (__attribute__((address_space(3))) void*)l, 16, 0, 0);
}

// ---------------- per-row LN stats (mu, rstd) ----------------
__global__ __launch_bounds__(64) void lnstats_kernel(const float* __restrict__ x,
                                                     float* __restrict__ st)
{
  int row = blockIdx.x, lane = threadIdx.x;
  const float* p = x + (size_t)row * DD;
  float s = 0.0f, sq = 0.0f;
  #pragma unroll
  for (int i = 0; i < 4; i++){
    float4 v = *(const float4*)(p + i * 256 + lane * 4);
    s  += v.x + v.y + v.z + v.w;
    sq += v.x*v.x + v.y*v.y + v.z*v.z + v.w*v.w;
  }
  #pragma unroll
  for (int m = 1; m < 64; m <<= 1){ s += __shfl_xor(s, m); sq += __shfl_xor(sq, m); }
  if (lane == 0){
    float mu  = s * (1.0f / DD);
    float var = sq * (1.0f / DD) - mu * mu;
    st[2*row]     = mu;
    st[2*row + 1] = 1.0f / sqrtf(var + 1e-5f);
  }
}

// ---------- LN apply + bf16(hi) convert (for fc1 A-plane) ----------
__global__ __launch_bounds__(256) void lncvt_kernel(const float* __restrict__ x,
    const float* __restrict__ st, const float* __restrict__ g,
    const float* __restrict__ b, us* __restrict__ out)
{
  int row = blockIdx.x, tid = threadIdx.x;
  float mu = st[2*row], rstd = st[2*row + 1];
  float4 xv = *(const float4*)(x + (size_t)row * DD + tid * 4);
  float4 gv = *(const float4*)(g + tid * 4);
  float4 bv = *(const float4*)(b + tid * 4);
  s4v o;
  o[0] = (short)f2bf((xv.x - mu) * rstd * gv.x + bv.x);
  o[1] = (short)f2bf((xv.y - mu) * rstd * gv.y + bv.y);
  o[2] = (short)f2bf((xv.z - mu) * rstd * gv.z + bv.z);
  o[3] = (short)f2bf((xv.w - mu) * rstd * gv.w + bv.w);
  *(s4v*)(out + (size_t)row * DD + tid * 4) = o;
}

// ---------- hidden -> hi/lo bf16 planes (enables pure-gl16 qkv pipeline) ----------
__global__ __launch_bounds__(256) void hsplit_kernel(const float* __restrict__ x,
    us* __restrict__ hh, us* __restrict__ hl)
{
  int row = blockIdx.x, tid = threadIdx.x;
  float4 v = *(const float4*)(x + (size_t)row * DD + tid * 4);
  unsigned h0, h1, l0, l1;
  splitpk(v.x, v.y, h0, l0);
  splitpk(v.z, v.w, h1, l1);
  uint2 hv = {h0, h1};
  uint2 lv = {l0, l1};
  *(uint2*)(hh + (size_t)row * DD + tid * 4) = hv;
  *(uint2*)(hl + (size_t)row * DD + tid * 4) = lv;
}

// ------------- weight transpose + bf16 hi/lo split (optional g-fold) -------------
__global__ __launch_bounds__(256) void wt_kernel(const float* __restrict__ src,
                                                 us* __restrict__ dhi,
                                                 us* __restrict__ dlo,
                                                 const float* __restrict__ gscale,
                                                 int K, int N)
{
  __shared__ float t[32][33];
  int tx = threadIdx.x, ty = threadIdx.y;
  int n0 = blockIdx.x * 32, k0 = blockIdx.y * 32;
  #pragma unroll
  for (int r = 0; r < 4; r++)
    t[ty + 8*r][tx] = src[(size_t)(k0 + ty + 8*r) * N + n0 + tx];
  __syncthreads();
  float gs = gscale ? gscale[k0 + tx] : 1.0f;
  #pragma unroll
  for (int r = 0; r < 4; r++){
    float f = t[tx][ty + 8*r] * gs;
    us hi = f2bf(f);
    size_t o = (size_t)(n0 + ty + 8*r) * K + k0 + tx;
    dhi[o] = hi;
    if (dlo) dlo[o] = f2bf(f - bf2f(hi));
  }
}

// ---- column sums: c1[n] = sum_k g_k W_kn, c2[n] = sum_k b_k W_kn (stacked QKV) ----
__global__ __launch_bounds__(256) void qc_kernel(const float* __restrict__ Wq,
    const float* __restrict__ Wk, const float* __restrict__ Wv,
    const float* __restrict__ g, const float* __restrict__ b,
    float* __restrict__ c1, float* __restrict__ c2)
{
  __shared__ float p1[4][64], p2[4][64];
  int n0 = blockIdx.x * 64;                 // 48 blocks over [0,3072)
  int kind = n0 >> 10, col0 = n0 & 1023;
  const float* W = (kind == 0) ? Wq : (kind == 1) ? Wk : Wv;
  int tx = threadIdx.x & 63, ty = threadIdx.x >> 6;
  float s1 = 0.0f, s2 = 0.0f;
  for (int k = ty; k < 1024; k += 4){
    float w = W[(size_t)k * 1024 + col0 + tx];
    s1 += g[k] * w;
    s2 += b[k] * w;
  }
  p1[ty][tx] = s1; p2[ty][tx] = s2;
  __syncthreads();
  if (ty == 0){
    c1[n0 + tx] = p1[0][tx] + p1[1][tx] + p1[2][tx] + p1[3][tx];
    c2[n0 + tx] = p2[0][tx] + p2[1][tx] + p2[2][tx] + p2[3][tx];
  }
}

// -------- fused QKV GEMM, LN folded into weights, 128x256 tile (2-barrier fallback) --------
__global__ __launch_bounds__(512) void qkv_kernel(const float* __restrict__ hidden,
    const us* __restrict__ WBh, const us* __restrict__ WBl,
    const float* __restrict__ bq, const float* __restrict__ bk, const float* __restrict__ bv,
    const float* __restrict__ lnstat, const float* __restrict__ c1, const float* __restrict__ c2,
    us* __restrict__ qhp, us* __restrict__ qlp, us* __restrict__ khp,
    us* __restrict__ klp, us* __restrict__ vhp, us* __restrict__ vlp)
{
  const int M = M1, K = DD;
  __shared__ __align__(16) us Ah[128*40];   // padded stride 40 u16 (2-way-free reads)
  __shared__ __align__(16) us Al[128*40];
  __shared__ __align__(16) us Bh[256*32];   // linear (gload_lds dest), src-XOR swizzled
  __shared__ __align__(16) us Bl[256*32];
  int tid = threadIdx.x;
  int m0 = blockIdx.y * 128, n0 = blockIdx.x * 256;
  int lane = tid & 63, w = tid >> 6;        // 8 waves
  int wr = w >> 2, wc = w & 3;              // 2 (M) x 4 (N)
  int fr = lane & 15, fq = lane >> 4;
  f4v acc[4][4];
  f4v zero = {0.0f, 0.0f, 0.0f, 0.0f};
  #pragma unroll
  for (int i = 0; i < 4; i++)
    #pragma unroll
    for (int j = 0; j < 4; j++) acc[i][j] = zero;
  int sr = tid >> 2, sc4 = (tid & 3) * 8;
  int ar = m0 + sr; if (ar >= M) ar = M - 1;
  int lr = lane >> 2, lc = (lane & 3) * 8;
  int gb0 = n0 + w*32 + lr;
  int swl = ((lr >> 1) & 3) << 3;
  int swr = ((fr >> 1) & 3) << 3;

  for (int kk = 0; kk < K; kk += 32){
    {
      const float* ap = hidden + (size_t)ar * K + kk + sc4;
      float4 fa = *(const float4*)(ap);
      float4 fb = *(const float4*)(ap + 4);
      unsigned h0, h1, h2, h3, l0, l1, l2, l3;
      splitpk(fa.x, fa.y, h0, l0);
      splitpk(fa.z, fa.w, h1, l1);
      splitpk(fb.x, fb.y, h2, l2);
      splitpk(fb.z, fb.w, h3, l3);
      uint4 hv = {h0, h1, h2, h3};
      uint4 lv = {l0, l1, l2, l3};
      *(uint4*)&Ah[sr*40 + sc4] = hv;
      *(uint4*)&Al[sr*40 + sc4] = lv;
    }
    gl16(WBh + (size_t)gb0 * K + kk + (lc ^ swl),        &Bh[(w*32)*32]);
    gl16(WBh + (size_t)(gb0 + 16) * K + kk + (lc ^ swl), &Bh[(w*32 + 16)*32]);
    gl16(WBl + (size_t)gb0 * K + kk + (lc ^ swl),        &Bl[(w*32)*32]);
    gl16(WBl + (size_t)(gb0 + 16) * K + kk + (lc ^ swl), &Bl[(w*32 + 16)*32]);
    __syncthreads();
    s8v ah[4], bh[4], al[4], bl[4];
    #pragma unroll
    for (int m = 0; m < 4; m++){
      ah[m] = *(const s8v*)&Ah[(wr*64 + m*16 + fr)*40 + fq*8];
      al[m] = *(const s8v*)&Al[(wr*64 + m*16 + fr)*40 + fq*8];
    }
    #pragma unroll
    for (int n = 0; n < 4; n++){
      bh[n] = *(const s8v*)&Bh[(wc*64 + n*16 + fr)*32 + (fq*8 ^ swr)];
      bl[n] = *(const s8v*)&Bl[(wc*64 + n*16 + fr)*32 + (fq*8 ^ swr)];
    }
    #pragma unroll
    for (int m = 0; m < 4; m++)
      #pragma unroll
      for (int n = 0; n < 4; n++){
        acc[m][n] = __builtin_amdgcn_mfma_f32_16x16x32_bf16(ah[m], bh[n], acc[m][n], 0, 0, 0);
        acc[m][n] = __builtin_amdgcn_mfma_f32_16x16x32_bf16(ah[m], bl[n], acc[m][n], 0, 0, 0);
        acc[m][n] = __builtin_amdgcn_mfma_f32_16x16x32_bf16(al[m], bh[n], acc[m][n], 0, 0, 0);
      }
    __syncthreads();
  }
  int kind = n0 >> 10;
  const float* bsel = (kind == 0) ? bq : (kind == 1) ? bk : bv;
  us* O0 = (kind == 0) ? qhp : (kind == 1) ? khp : vhp;
  us* O1 = (kind == 0) ? qlp : (kind == 1) ? klp : vlp;
  float scl = (kind == 0) ? 0.125f : 1.0f;
  float C1r[4], C2r[4];
  int h2r[4], d2r[4];
  #pragma unroll
  for (int n = 0; n < 4; n++){
    int gcol = n0 + wc*64 + n*16 + fr;
    int lcn = gcol & 1023;
    h2r[n] = lcn >> 6; d2r[n] = lcn & 63;
    C1r[n] = c1[gcol];
    C2r[n] = c2[gcol] + bsel[lcn];
  }
  #pragma unroll
  for (int m = 0; m < 4; m++){
    int grow0 = m0 + wr*64 + m*16 + fq*4;
    #pragma unroll
    for (int i = 0; i < 4; i++){
      int grow = grow0 + i;
      if (grow < M){
        float mu = lnstat[2*grow], rstd = lnstat[2*grow + 1];
        int b2 = grow / 257, t2 = grow - b2 * 257;
        size_t rb = ((size_t)(b2*16) * 257 + t2) * 64;
        #pragma unroll
        for (int n = 0; n < 4; n++){
          size_t off2 = rb + (size_t)h2r[n] * (257*64) + d2r[n];
          float v = (rstd * acc[m][n][i] - rstd * mu * C1r[n] + C2r[n]) * scl;
          us hi = f2bf(v);
          O0[off2] = hi;
          O1[off2] = f2bf(v - bf2f(hi));
        }
      }
    }
  }
}

// ---- QKV pipelined: pure-gl16 staging from pre-split hidden planes, counted vmcnt ----
// Structure = gemm8p (proven): 3-deep bufs, no ds_writes -> no lgkmcnt drain.
// Tile 128(M)x256(N), 8 waves, wave tile 64x64, 3-term split MFMA.
__global__ __launch_bounds__(512) void qkvp_kernel(const us* __restrict__ Hh,
    const us* __restrict__ Hl, const us* __restrict__ WBh, const us* __restrict__ WBl,
    const float* __restrict__ bq, const float* __restrict__ bk, const float* __restrict__ bv,
    const float* __restrict__ lnstat, const float* __restrict__ c1, const float* __restrict__ c2,
    us* __restrict__ qhp, us* __restrict__ qlp, us* __restrict__ khp,
    us* __restrict__ klp, us* __restrict__ vhp, us* __restrict__ vlp)
{
  const int M = M1, K = DD;
  __shared__ __align__(16) us Ah3[3][128*32];   // 8KB each
  __shared__ __align__(16) us Al3[3][128*32];
  __shared__ __align__(16) us Bh3[3][256*32];   // 16KB each
  __shared__ __align__(16) us Bl3[3][256*32];   // 144KB total
  int tid = threadIdx.x;
  int m0 = blockIdx.y * 128, n0 = blockIdx.x * 256;
  int lane = tid & 63, w = tid >> 6;        // 8 waves
  int wr = w >> 2, wc = w & 3;              // 2 (M) x 4 (N)
  int fr = lane & 15, fq = lane >> 4;
  f4v acc[4][4];
  f4v zero = {0.0f, 0.0f, 0.0f, 0.0f};
  #pragma unroll
  for (int i = 0; i < 4; i++)
    #pragma unroll
    for (int j = 0; j < 4; j++) acc[i][j] = zero;
  // staging: wave w covers rows [w*16, w*16+16); 1KB per wave per stream-half
  int srow = w*16 + (lane >> 2);            // 0..127
  int o16 = ((lane & 3) * 8) ^ (((srow >> 1) & 3) << 3);
  int swr = ((fr >> 1) & 3) << 3;
  int aR = m0 + srow; if (aR >= M) aR = M - 1;
  int bR0 = n0 + srow;
  int bR1 = n0 + 128 + srow;
  int ldst = w * 512;                       // u16 offset of wave's 1KB slab

  const int NT = K >> 5;                    // 32
  #pragma unroll
  for (int t0 = 0; t0 < 2; t0++){
    int kk = t0 * 32;
    gl16(Hh  + (size_t)aR  * K + kk + o16, &Ah3[t0][ldst]);
    gl16(Hl  + (size_t)aR  * K + kk + o16, &Al3[t0][ldst]);
    gl16(WBh + (size_t)bR0 * K + kk + o16, &Bh3[t0][ldst]);
    gl16(WBh + (size_t)bR1 * K + kk + o16, &Bh3[t0][4096 + ldst]);
    gl16(WBl + (size_t)bR0 * K + kk + o16, &Bl3[t0][ldst]);
    gl16(WBl + (size_t)bR1 * K + kk + o16, &Bl3[t0][4096 + ldst]);
  }
  asm volatile("s_waitcnt vmcnt(6)" ::: "memory");   // tile 0 complete
  __builtin_amdgcn_s_barrier();

  int buf = 0;
  #pragma unroll 1
  for (int t = 0; t < NT; ++t){
    int nbuf = buf + 2; if (nbuf >= 3) nbuf -= 3;
    bool pf = (t + 2) < NT;
    int kk2 = (t + 2) * 32;
    s8v ah[4], al[4], bh[4], bl[4];
    #pragma unroll
    for (int m = 0; m < 4; m++){
      int r = wr*64 + m*16 + fr;
      ah[m] = *(const s8v*)&Ah3[buf][r*32 + (fq*8 ^ swr)];
      al[m] = *(const s8v*)&Al3[buf][r*32 + (fq*8 ^ swr)];
    }
    #pragma unroll
    for (int n = 0; n < 4; n++){
      int r = wc*64 + n*16 + fr;
      bh[n] = *(const s8v*)&Bh3[buf][r*32 + (fq*8 ^ swr)];
      bl[n] = *(const s8v*)&Bl3[buf][r*32 + (fq*8 ^ swr)];
    }
    if (pf){
      gl16(Hh  + (size_t)aR  * K + kk2 + o16, &Ah3[nbuf][ldst]);
      gl16(Hl  + (size_t)aR  * K + kk2 + o16, &Al3[nbuf][ldst]);
      gl16(WBh + (size_t)bR0 * K + kk2 + o16, &Bh3[nbuf][ldst]);
      gl16(WBh + (size_t)bR1 * K + kk2 + o16, &Bh3[nbuf][4096 + ldst]);
      gl16(WBl + (size_t)bR0 * K + kk2 + o16, &Bl3[nbuf][ldst]);
      gl16(WBl + (size_t)bR1 * K + kk2 + o16, &Bl3[nbuf][4096 + ldst]);
    }
    __builtin_amdgcn_s_barrier();
    __builtin_amdgcn_s_setprio(1);
    #pragma unroll
    for (int m = 0; m < 4; m++)
      #pragma unroll
      for (int n = 0; n < 4; n++){
        acc[m][n] = __builtin_amdgcn_mfma_f32_16x16x32_bf16(ah[m], bh[n], acc[m][n], 0, 0, 0);
        acc[m][n] = __builtin_amdgcn_mfma_f32_16x16x32_bf16(ah[m], bl[n], acc[m][n], 0, 0, 0);
        acc[m][n] = __builtin_amdgcn_mfma_f32_16x16x32_bf16(al[m], bh[n], acc[m][n], 0, 0, 0);
      }
    __builtin_amdgcn_s_setprio(0);
    if (t + 1 < NT){
      if (pf) asm volatile("s_waitcnt vmcnt(6)" ::: "memory");
      else    asm volatile("s_waitcnt vmcnt(0)" ::: "memory");
    }
    __builtin_amdgcn_s_barrier();
    buf = buf + 1; if (buf >= 3) buf = 0;
  }
  // epilogue: LN completion + head-major dual-plane write, kind select
  int kind = n0 >> 10;
  const float* bsel = (kind == 0) ? bq : (kind == 1) ? bk : bv;
  us* O0 = (kind == 0) ? qhp : (kind == 1) ? khp : vhp;
  us* O1 = (kind == 0) ? qlp : (kind == 1) ? klp : vlp;
  float scl = (kind == 0) ? 0.125f : 1.0f;
  float C1r[4], C2r[4];
  int h2r[4], d2r[4];
  #pragma unroll
  for (int n = 0; n < 4; n++){
    int gcol = n0 + wc*64 + n*16 + fr;
    int lcn = gcol & 1023;
    h2r[n] = lcn >> 6; d2r[n] = lcn & 63;
    C1r[n] = c1[gcol];
    C2r[n] = c2[gcol] + bsel[lcn];
  }
  #pragma unroll
  for (int m = 0; m < 4; m++){
    int grow0 = m0 + wr*64 + m*16 + fq*4;
    #pragma unroll
    for (int i = 0; i < 4; i++){
      int grow = grow0 + i;
      if (grow < M){
        float mu = lnstat[2*grow], rstd = lnstat[2*grow + 1];
        int b2 = grow / 257, t2 = grow - b2 * 257;
        size_t rb = ((size_t)(b2*16) * 257 + t2) * 64;
        #pragma unroll
        for (int n = 0; n < 4; n++){
          size_t off2 = rb + (size_t)h2r[n] * (257*64) + d2r[n];
          float v = (rstd * acc[m][n][i] - rstd * mu * C1r[n] + C2r[n]) * scl;
          us hi = f2bf(v);
          O0[off2] = hi;
          O1[off2] = f2bf(v - bf2f(hi));
        }
      }
    }
  }
}

// ---------------- 128x128 MFMA GEMM, gload_lds staging (Wo) ----------------
template<int AMODE, int SPLIT, int EPI>
__global__ __launch_bounds__(256) void gemm2_kernel(const us* __restrict__ Ahp,
    const us* __restrict__ Alp,
    const us* __restrict__ BTh, const us* __restrict__ BTl,
    const float* __restrict__ bias, const float* __restrict__ resid,
    void* __restrict__ C0, void* __restrict__ C1, int M, int N, int K)
{
  __shared__ __align__(16) us Ah[128*32];
  __shared__ __align__(16) us Bh[128*32];
  __shared__ __align__(16) us Al[SPLIT ? 128*32 : 8];
  __shared__ __align__(16) us Bl[SPLIT ? 128*32 : 8];
  int tid = threadIdx.x;
  int m0 = blockIdx.y * 128, n0 = blockIdx.x * 128;
  int lane = tid & 63, w = tid >> 6;
  int wr = w >> 1, wc = w & 1;
  int fr = lane & 15, fq = lane >> 4;
  f4v acc[4][4];
  f4v zero = {0.0f, 0.0f, 0.0f, 0.0f};
  #pragma unroll
  for (int i = 0; i < 4; i++)
    #pragma unroll
    for (int j = 0; j < 4; j++) acc[i][j] = zero;
  int lr = lane >> 2, lc = (lane & 3) * 8;
  int swl = ((lr >> 1) & 3) << 3;
  int swr = ((fr >> 1) & 3) << 3;
  int ga0 = m0 + w*32 + lr;      if (ga0 >= M) ga0 = M - 1;
  int ga1 = m0 + w*32 + 16 + lr; if (ga1 >= M) ga1 = M - 1;
  int gb0 = n0 + w*32 + lr;
  int b2a = ga0 / 257, t2a = ga0 - b2a * 257;
  int b2b = ga1 / 257, t2b = ga1 - b2b * 257;

  for (int kk = 0; kk < K; kk += 32){
    if (AMODE == 1){
      gl16(Ahp + (size_t)ga0 * K + kk + (lc ^ swl), &Ah[(w*32)*32]);
      gl16(Ahp + (size_t)ga1 * K + kk + (lc ^ swl), &Ah[(w*32 + 16)*32]);
      if (SPLIT){
        gl16(Alp + (size_t)ga0 * K + kk + (lc ^ swl), &Al[(w*32)*32]);
        gl16(Alp + (size_t)ga1 * K + kk + (lc ^ swl), &Al[(w*32 + 16)*32]);
      }
    } else {
      int h2 = kk >> 6, d2 = (kk & 63) + (lc ^ swl);
      size_t o0 = ((size_t)(b2a*16 + h2) * 257 + t2a) * 64 + d2;
      size_t o1 = ((size_t)(b2b*16 + h2) * 257 + t2b) * 64 + d2;
      gl16(Ahp + o0, &Ah[(w*32)*32]);
      gl16(Ahp + o1, &Ah[(w*32 + 16)*32]);
      if (SPLIT){
        gl16(Alp + o0, &Al[(w*32)*32]);
        gl16(Alp + o1, &Al[(w*32 + 16)*32]);
      }
    }
    gl16(BTh + (size_t)gb0 * K + kk + (lc ^ swl),        &Bh[(w*32)*32]);
    gl16(BTh + (size_t)(gb0 + 16) * K + kk + (lc ^ swl), &Bh[(w*32 + 16)*32]);
    if (SPLIT){
      gl16(BTl + (size_t)gb0 * K + kk + (lc ^ swl),        &Bl[(w*32)*32]);
      gl16(BTl + (size_t)(gb0 + 16) * K + kk + (lc ^ swl), &Bl[(w*32 + 16)*32]);
    }
    __syncthreads();
    s8v ah[4], bh[4], al[4], bl[4];
    #pragma unroll
    for (int m = 0; m < 4; m++){
      ah[m] = *(const s8v*)&Ah[(wr*64 + m*16 + fr)*32 + (fq*8 ^ swr)];
      if (SPLIT) al[m] = *(const s8v*)&Al[(wr*64 + m*16 + fr)*32 + (fq*8 ^ swr)];
    }
    #pragma unroll
    for (int n = 0; n < 4; n++){
      bh[n] = *(const s8v*)&Bh[(wc*64 + n*16 + fr)*32 + (fq*8 ^ swr)];
      if (SPLIT) bl[n] = *(const s8v*)&Bl[(wc*64 + n*16 + fr)*32 + (fq*8 ^ swr)];
    }
    #pragma unroll
    for (int m = 0; m < 4; m++)
      #pragma unroll
      for (int n = 0; n < 4; n++){
        acc[m][n] = __builtin_amdgcn_mfma_f32_16x16x32_bf16(ah[m], bh[n], acc[m][n], 0, 0, 0);
        if (SPLIT){
          acc[m][n] = __builtin_amdgcn_mfma_f32_16x16x32_bf16(ah[m], bl[n], acc[m][n], 0, 0, 0);
          acc[m][n] = __builtin_amdgcn_mfma_f32_16x16x32_bf16(al[m], bh[n], acc[m][n], 0, 0, 0);
        }
      }
    __syncthreads();
  }
  #pragma unroll
  for (int m = 0; m < 4; m++){
    int grow0 = m0 + wr*64 + m*16 + fq*4;
    #pragma unroll
    for (int n = 0; n < 4; n++){
      int gcol = n0 + wc*64 + n*16 + fr;
      float bcol = bias[gcol];
      #pragma unroll
      for (int i = 0; i < 4; i++){
        int grow = grow0 + i;
        if (grow < M){
          float v = acc[m][n][i] + bcol;
          size_t off = (size_t)grow * N + gcol;
          if (EPI == 1){
            ((float*)C0)[off] = v + resid[off];
          } else if (EPI == 2){
            float gq = v / (1.0f + expf(-1.702f * v));
            ((us*)C0)[off] = f2bf(gq);
          } else {
            float x = v + resid[off];
            us h, l;
            split1(x, h, l);
            ((us*)C0)[off] = h;
            ((us*)C1)[off] = l;
          }
        }
      }
    }
  }
}

// ------- 256x256 counted-vmcnt pipelined GEMM (fc1/fc2), plain bf16 -------
template<int EPI>
__global__ __launch_bounds__(512) void gemm8p_kernel(const us* __restrict__ A,
    const us* __restrict__ B, const float* __restrict__ bias,
    const float* __restrict__ resid, void* __restrict__ C, int M, int N, int K)
{
  __shared__ __align__(16) us As[3][256*32];   // 16KB each
  __shared__ __align__(16) us Bs[3][256*32];
  int tid = threadIdx.x;
  int m0 = blockIdx.y * 256, n0 = blockIdx.x * 256;
  int lane = tid & 63, w = tid >> 6;           // 8 waves
  int wr = w >> 2, wc = w & 3;                 // wave tile 128x64
  int fr = lane & 15, fq = lane >> 4;
  f4v acc[8][4];
  f4v zero = {0.0f, 0.0f, 0.0f, 0.0f};
  #pragma unroll
  for (int i = 0; i < 8; i++)
    #pragma unroll
    for (int j = 0; j < 4; j++) acc[i][j] = zero;
  int srow = w*16 + (lane >> 2);
  int aR0 = m0 + srow;        if (aR0 >= M) aR0 = M - 1;
  int aR1 = m0 + 128 + srow;  if (aR1 >= M) aR1 = M - 1;
  int bR0 = n0 + srow;
  int bR1 = n0 + 128 + srow;
  int o16 = ((lane & 3) * 8) ^ (((srow >> 1) & 3) << 3);   // 16B-granule src XOR
  int swr = ((fr >> 1) & 3) << 3;
  int ldst = w * 512;                                      // u16, + r*4096

  const int NT = K >> 5;
  #pragma unroll
  for (int t0 = 0; t0 < 2; t0++){
    gl16(A + (size_t)aR0 * K + t0*32 + o16, &As[t0][ldst]);
    gl16(B + (size_t)bR0 * K + t0*32 + o16, &Bs[t0][ldst]);
    gl16(A + (size_t)aR1 * K + t0*32 + o16, &As[t0][4096 + ldst]);
    gl16(B + (size_t)bR1 * K + t0*32 + o16, &Bs[t0][4096 + ldst]);
  }
  asm volatile("s_waitcnt vmcnt(4)" ::: "memory");
  __builtin_amdgcn_s_barrier();

  int buf = 0;
  #pragma unroll 1
  for (int t = 0; t < NT; ++t){
    int nbuf = buf + 2; if (nbuf >= 3) nbuf -= 3;
    bool pf = (t + 2) < NT;
    int kk2 = (t + 2) * 32;
    us* Ab = As[buf];
    us* Bb = Bs[buf];
    {
      s8v a[4], b[4];
      #pragma unroll
      for (int mt = 0; mt < 4; mt++){
        int r = wr*128 + mt*16 + fr;
        a[mt] = *(const s8v*)&Ab[r*32 + (fq*8 ^ swr)];
      }
      #pragma unroll
      for (int nt = 0; nt < 4; nt++){
        int r = wc*64 + nt*16 + fr;
        b[nt] = *(const s8v*)&Bb[r*32 + (fq*8 ^ swr)];
      }
      if (pf){
        gl16(A + (size_t)aR0 * K + kk2 + o16, &As[nbuf][ldst]);
        gl16(B + (size_t)bR0 * K + kk2 + o16, &Bs[nbuf][ldst]);
      }
      __builtin_amdgcn_s_barrier();
      __builtin_amdgcn_s_setprio(1);
      #pragma unroll
      for (int mt = 0; mt < 4; mt++)
        #pragma unroll
        for (int nt = 0; nt < 4; nt++)
          acc[mt][nt] = __builtin_amdgcn_mfma_f32_16x16x32_bf16(a[mt], b[nt], acc[mt][nt], 0, 0, 0);
      __builtin_amdgcn_s_setprio(0);
      __builtin_amdgcn_s_barrier();
    }
    {
      s8v a[4], b[4];
      #pragma unroll
      for (int mt = 0; mt < 4; mt++){
        int r = wr*128 + 64 + mt*16 + fr;
        a[mt] = *(const s8v*)&Ab[r*32 + (fq*8 ^ swr)];
      }
      #pragma unroll
      for (int nt = 0; nt < 4; nt++){
        int r = wc*64 + nt*16 + fr;
        b[nt] = *(const s8v*)&Bb[r*32 + (fq*8 ^ swr)];
      }
      if (pf){
        gl16(A + (size_t)aR1 * K + kk2 + o16, &As[nbuf][4096 + ldst]);
        gl16(B + (size_t)bR1 * K + kk2 + o16, &Bs[nbuf][4096 + ldst]);
      }
      __builtin_amdgcn_s_barrier();
      __builtin_amdgcn_s_setprio(1);
      #pragma unroll
      for (int mt = 0; mt < 4; mt++)
        #pragma unroll
        for (int nt = 0; nt < 4; nt++)
          acc[4 + mt][nt] = __builtin_amdgcn_mfma_f32_16x16x32_bf16(a[mt], b[nt], acc[4 + mt][nt], 0, 0, 0);
      __builtin_amdgcn_s_setprio(0);
    }
    if (t + 1 < NT){
      if (pf) asm volatile("s_waitcnt vmcnt(4)" ::: "memory");
      else    asm volatile("s_waitcnt vmcnt(0)" ::: "memory");
    }
    __builtin_amdgcn_s_barrier();
    buf = buf + 1; if (buf >= 3) buf = 0;
  }
  #pragma unroll
  for (int mh = 0; mh < 2; mh++)
    #pragma unroll
    for (int mt = 0; mt < 4; mt++){
      int grow0 = m0 + wr*128 + mh*64 + mt*16 + fq*4;
      #pragma unroll
      for (int nt = 0; nt < 4; nt++){
        int gcol = n0 + wc*64 + nt*16 + fr;
        float bcol = bias[gcol];
        #pragma unroll
        for (int i = 0; i < 4; i++){
          int grow = grow0 + i;
          if (grow < M){
            float v = acc[mh*4 + mt][nt][i] + bcol;
            size_t off = (size_t)grow * N + gcol;
            if (EPI == 1){
              ((float*)C)[off] = v + resid[off];
            } else {
              float gq = v / (1.0f + expf(-1.702f * v));
              ((us*)C)[off] = f2bf(gq);
            }
          }
        }
      }
    }
}

// ------- flash MFMA split-bf16 attention, head-major planes; O aliases Q -------
__global__ __launch_bounds__(512, 1) void attn_flash_kernel(
    const us* __restrict__ Qh, const us* __restrict__ Ql,
    const us* __restrict__ Kh, const us* __restrict__ Klo,
    const us* __restrict__ Vh, const us* __restrict__ Vlo,
    us* Oh, us* Ol)
{
  __shared__ __align__(16) us Kl[257 * 128];  // 65,792 B
  __shared__ __align__(16) us Vl[64 * 640];   // 81,920 B
  int bh = blockIdx.x;
  const size_t hb = (size_t)bh * 257 * 64;
  int tid = threadIdx.x;
  int l = tid & 63, w = tid >> 6;  // w in 0..7
  int g = l >> 4, c = l & 15;
  const float NEG = -3.0e38f;

  {
    s8v z8 = {0,0,0,0,0,0,0,0};
    for (int idx = tid; idx < 64*640/8; idx += 512)
      *((s8v*)Vl + idx) = z8;
  }
  __syncthreads();
  for (int idx = tid; idx < 257*8; idx += 512){
    int tok = idx >> 3, ch = idx & 7;
    int sw = (tok & 7) << 4;
    s8v hv = *(const s8v*)(Kh  + hb + (size_t)tok * 64 + ch*8);
    s8v lv = *(const s8v*)(Klo + hb + (size_t)tok * 64 + ch*8);
    char* kr = (char*)Kl + tok * 256;
    *(s8v*)(kr + ((ch*16) ^ sw)) = hv;
    *(s8v*)(kr + 128 + ((ch*16) ^ sw)) = lv;
  }
  for (int idx = tid; idx < 257*8; idx += 512){
    int tok = idx >> 3, ch = idx & 7;
    s8v hv = *(const s8v*)(Vh  + hb + (size_t)tok * 64 + ch*8);
    s8v lv = *(const s8v*)(Vlo + hb + (size_t)tok * 64 + ch*8);
    #pragma unroll
    for (int j = 0; j < 8; j++){
      int d = ch*8 + j;
      char* vr = (char*)Vl + d * 1280;
      int off = (tok * 2) ^ (j << 4);
      *(us*)(vr + off) = (us)hv[j];
      *(us*)(vr + 640 + off) = (us)lv[j];
    }
  }
  __syncthreads();

  for (int qt = w; qt < 17; qt += 8){
    int t0 = qt * 16;
    int qr = t0 + c; if (qr > 256) qr = 256;
    const us* qp  = Qh + hb + (size_t)qr * 64 + g*8;
    const us* qp2 = Ql + hb + (size_t)qr * 64 + g*8;
    s8v qhi[2], qlo[2];
    qhi[0] = *(const s8v*)(qp);       qhi[1] = *(const s8v*)(qp + 32);
    qlo[0] = *(const s8v*)(qp2);      qlo[1] = *(const s8v*)(qp2 + 32);

    float m_run = NEG, l_run = 0.0f;
    f4v o4[4];
    #pragma unroll
    for (int dt = 0; dt < 4; dt++) o4[dt] = (f4v){0.0f, 0.0f, 0.0f, 0.0f};

    #pragma unroll 1
    for (int mck = 0; mck < 9; mck++){
      f4v a0, a1;
      {
        int t = 2*mck;
        int krow = t * 16 + c; if (krow > 256) krow = 256;
        char* kr = (char*)Kl + krow * 256;
        int sw = (krow & 7) << 4;
        s8v khi0 = *(const s8v*)(kr + ((g * 16) ^ sw));
        s8v khi1 = *(const s8v*)(kr + ((64 + g * 16) ^ sw));
        s8v klo0 = *(const s8v*)(kr + 128 + ((g * 16) ^ sw));
        s8v klo1 = *(const s8v*)(kr + 128 + ((64 + g * 16) ^ sw));
        f4v a = {0.0f, 0.0f, 0.0f, 0.0f};
        a = __builtin_amdgcn_mfma_f32_16x16x32_bf16(khi0, qhi[0], a, 0, 0, 0);
        a = __builtin_amdgcn_mfma_f32_16x16x32_bf16(khi1, qhi[1], a, 0, 0, 0);
        a = __builtin_amdgcn_mfma_f32_16x16x32_bf16(khi0, qlo[0], a, 0, 0, 0);
        a = __builtin_amdgcn_mfma_f32_16x16x32_bf16(khi1, qlo[1], a, 0, 0, 0);
        a = __builtin_amdgcn_mfma_f32_16x16x32_bf16(klo0, qhi[0], a, 0, 0, 0);
        a = __builtin_amdgcn_mfma_f32_16x16x32_bf16(klo1, qhi[1], a, 0, 0, 0);
        a0 = a;
      }
      if (mck < 8){
        int t = 2*mck + 1;
        int krow = t * 16 + c; if (krow > 256) krow = 256;
        char* kr = (char*)Kl + krow * 256;
        int sw = (krow & 7) << 4;
        s8v khi0 = *(const s8v*)(kr + ((g * 16) ^ sw));
        s8v khi1 = *(const s8v*)(kr + ((64 + g * 16) ^ sw));
        s8v klo0 = *(const s8v*)(kr + 128 + ((g * 16) ^ sw));
        s8v klo1 = *(const s8v*)(kr + 128 + ((64 + g * 16) ^ sw));
        f4v a = {0.0f, 0.0f, 0.0f, 0.0f};
        a = __builtin_amdgcn_mfma_f32_16x16x32_bf16(khi0, qhi[0], a, 0, 0, 0);
        a = __builtin_amdgcn_mfma_f32_16x16x32_bf16(khi1, qhi[1], a, 0, 0, 0);
        a = __builtin_amdgcn_mfma_f32_16x16x32_bf16(khi0, qlo[0], a, 0, 0, 0);
        a = __builtin_amdgcn_mfma_f32_16x16x32_bf16(khi1, qlo[1], a, 0, 0, 0);
        a = __builtin_amdgcn_mfma_f32_16x16x32_bf16(klo0, qhi[0], a, 0, 0, 0);
        a = __builtin_amdgcn_mfma_f32_16x16x32_bf16(klo1, qhi[1], a, 0, 0, 0);
        a1 = a;
      } else {
        a1 = (f4v){NEG, NEG, NEG, NEG};
        a0[0] = (g == 0) ? a0[0] : NEG;
        a0[1] = NEG; a0[2] = NEG; a0[3] = NEG;
      }
      float cm = fmaxf(fmaxf(fmaxf(a0[0], a0[1]), fmaxf(a0[2], a0[3])),
                       fmaxf(fmaxf(a1[0], a1[1]), fmaxf(a1[2], a1[3])));
      cm = fmaxf(cm, __shfl_xor(cm, 16));
      cm = fmaxf(cm, __shfl_xor(cm, 32));
      float m_new = fmaxf(m_run, cm);
      float scl = __expf(m_run - m_new);
      m_run = m_new;
      l_run *= scl;
      #pragma unroll
      for (int dt = 0; dt < 4; dt++){
        o4[dt][0] *= scl; o4[dt][1] *= scl; o4[dt][2] *= scl; o4[dt][3] *= scl;
      }
      float ls = 0.0f;
      unsigned Ph2[2][2], Pl2[2][2];
      #pragma unroll
      for (int k2 = 0; k2 < 2; k2++){
        float e0 = __expf(a0[2*k2] - m_new), e1 = __expf(a0[2*k2+1] - m_new);
        ls += e0 + e1;
        us h0 = f2bf(e0), h1 = f2bf(e1);
        Ph2[0][k2] = (unsigned)h0 | ((unsigned)h1 << 16);
        Pl2[0][k2] = (unsigned)f2bf(e0 - bf2f(h0)) | ((unsigned)f2bf(e1 - bf2f(h1)) << 16);
        float e2 = __expf(a1[2*k2] - m_new), e3 = __expf(a1[2*k2+1] - m_new);
        ls += e2 + e3;
        us h2 = f2bf(e2), h3 = f2bf(e3);
        Ph2[1][k2] = (unsigned)h2 | ((unsigned)h3 << 16);
        Pl2[1][k2] = (unsigned)f2bf(e2 - bf2f(h2)) | ((unsigned)f2bf(e3 - bf2f(h3)) << 16);
      }
      l_run += ls;
      s8v pbh, pbl;
      #pragma unroll
      for (int ww = 0; ww < 4; ww++){
        int srcl = (((g & 1) * 2 + (ww >> 1)) << 4) | c;
        unsigned h0 = (unsigned)__shfl((int)Ph2[0][ww & 1], srcl, 64);
        unsigned lo0 = (unsigned)__shfl((int)Pl2[0][ww & 1], srcl, 64);
        unsigned h1 = (unsigned)__shfl((int)Ph2[1][ww & 1], srcl, 64);
        unsigned lo1 = (unsigned)__shfl((int)Pl2[1][ww & 1], srcl, 64);
        ((unsigned*)&pbh)[ww] = (g >> 1) ? h1 : h0;
        ((unsigned*)&pbl)[ww] = (g >> 1) ? lo1 : lo0;
      }
      #pragma unroll
      for (int dt = 0; dt < 4; dt++){
        int d = dt * 16 + c;
        char* vr = (char*)Vl + d * 1280;
        int off = (mck * 64 + g * 16) ^ ((d & 7) << 4);
        s8v vh = *(const s8v*)(vr + off);
        s8v vlo = *(const s8v*)(vr + 640 + off);
        o4[dt] = __builtin_amdgcn_mfma_f32_16x16x32_bf16(vh, pbh, o4[dt], 0, 0, 0);
        o4[dt] = __builtin_amdgcn_mfma_f32_16x16x32_bf16(vh, pbl, o4[dt], 0, 0, 0);
        o4[dt] = __builtin_amdgcn_mfma_f32_16x16x32_bf16(vlo, pbh, o4[dt], 0, 0, 0);
      }
    }
    l_run += __shfl_xor(l_run, 16);
    l_run += __shfl_xor(l_run, 32);
    float inv = 1.0f / l_run;
    int qrow = t0 + c;
    if (qrow <= 256){
      us* oph = Oh + hb + (size_t)qrow * 64;
      us* opl = Ol + hb + (size_t)qrow * 64;
      #pragma unroll
      for (int dt = 0; dt < 4; dt++){
        s4v hv4, lv4;
        #pragma unroll
        for (int i = 0; i < 4; i++){
          float ov = o4[dt][i] * inv;
          us hi = f2bf(ov);
          hv4[i] = (short)hi;
          lv4[i] = (short)f2bf(ov - bf2f(hi));
        }
        *(s4v*)(oph + dt*16 + g*4) = hv4;
        *(s4v*)(opl + dt*16 + g*4) = lv4;
      }
    }
  }
}

// ---------------- row norms from hi/lo planes ----------------
__global__ __launch_bounds__(64) void norms_kernel(const us* __restrict__ xh,
    const us* __restrict__ xl, float* __restrict__ nrm)
{
  int row = blockIdx.x, lane = threadIdx.x;
  const us* ph = xh + (size_t)row * DD + lane * 16;
  const us* pl = xl + (size_t)row * DD + lane * 16;
  float sq = 0.0f;
  #pragma unroll
  for (int i = 0; i < 2; i++){
    s8v h = *(const s8v*)(ph + i * 8);
    s8v l = *(const s8v*)(pl + i * 8);
    #pragma unroll
    for (int j = 0; j < 8; j++){
      float v = bf2f((us)h[j]) + bf2f((us)l[j]);
      sq += v * v;
    }
  }
  #pragma unroll
  for (int m = 1; m < 64; m <<= 1) sq += __shfl_xor(sq, m);
  if (lane == 0) nrm[row] = sqrtf(sq);
}

// ------- cosine scores via split-bf16 MFMA (even x odd tokens) -------
__global__ __launch_bounds__(256) void scores8_kernel(const us* __restrict__ xh,
    const us* __restrict__ xl, const float* __restrict__ nrm, float* __restrict__ sc)
{
  __shared__ __align__(16) us Ah[128*32];
  __shared__ __align__(16) us Al[128*32];
  __shared__ __align__(16) us Bh[128*32];
  __shared__ __align__(16) us Bl[128*32];
  int mblk = blockIdx.x, b = blockIdx.y;
  const size_t rb = (size_t)b * TT * DD;
  int tid = threadIdx.x;
  int lane = tid & 63, w = tid >> 6;
  int wr = w >> 1, wc = w & 1;
  int fr = lane & 15, fq = lane >> 4;
  f4v acc[4][4];
  f4v zero = {0.0f, 0.0f, 0.0f, 0.0f};
  #pragma unroll
  for (int i = 0; i < 4; i++)
    #pragma unroll
    for (int j = 0; j < 4; j++) acc[i][j] = zero;
  int lr = lane >> 2, lc = (lane & 3) * 8;
  int swl = ((lr >> 1) & 3) << 3;
  int swr = ((fr >> 1) & 3) << 3;
  int ra0 = mblk*128 + w*32 + lr;      if (ra0 > 128) ra0 = 128;
  int ra1 = mblk*128 + w*32 + 16 + lr; if (ra1 > 128) ra1 = 128;
  size_t ta0 = (size_t)(2 * ra0) * DD, ta1 = (size_t)(2 * ra1) * DD;
  size_t tb0 = (size_t)(2 * (w*32 + lr) + 1) * DD;
  size_t tb1 = (size_t)(2 * (w*32 + 16 + lr) + 1) * DD;

  for (int kk = 0; kk < DD; kk += 32){
    int co = kk + (lc ^ swl);
    gl16(xh + rb + ta0 + co, &Ah[(w*32)*32]);
    gl16(xh + rb + ta1 + co, &Ah[(w*32 + 16)*32]);
    gl16(xl + rb + ta0 + co, &Al[(w*32)*32]);
    gl16(xl + rb + ta1 + co, &Al[(w*32 + 16)*32]);
    gl16(xh + rb + tb0 + co, &Bh[(w*32)*32]);
    gl16(xh + rb + tb1 + co, &Bh[(w*32 + 16)*32]);
    gl16(xl + rb + tb0 + co, &Bl[(w*32)*32]);
    gl16(xl + rb + tb1 + co, &Bl[(w*32 + 16)*32]);
    __syncthreads();
    s8v ah[4], bh[4], al[4], bl[4];
    #pragma unroll
    for (int m = 0; m < 4; m++){
      ah[m] = *(const s8v*)&Ah[(wr*64 + m*16 + fr)*32 + (fq*8 ^ swr)];
      al[m] = *(const s8v*)&Al[(wr*64 + m*16 + fr)*32 + (fq*8 ^ swr)];
    }
    #pragma unroll
    for (int n = 0; n < 4; n++){
      bh[n] = *(const s8v*)&Bh[(wc*64 + n*16 + fr)*32 + (fq*8 ^ swr)];
      bl[n] = *(const s8v*)&Bl[(wc*64 + n*16 + fr)*32 + (fq*8 ^ swr)];
    }
    #pragma unroll
    for (int m = 0; m < 4; m++)
      #pragma unroll
      for (int n = 0; n < 4; n++){
        acc[m][n] = __builtin_amdgcn_mfma_f32_16x16x32_bf16(ah[m], bh[n], acc[m][n], 0, 0, 0);
        acc[m][n] = __builtin_amdgcn_mfma_f32_16x16x32_bf16(ah[m], bl[n], acc[m][n], 0, 0, 0);
        acc[m][n] = __builtin_amdgcn_mfma_f32_16x16x32_bf16(al[m], bh[n], acc[m][n], 0, 0, 0);
      }
    __syncthreads();
  }
  #pragma unroll
  for (int m = 0; m < 4; m++){
    int grow0 = mblk*128 + wr*64 + m*16 + fq*4;
    #pragma unroll
    for (int n = 0; n < 4; n++){
      int gcol = wc*64 + n*16 + fr;
      float no = nrm[(size_t)b * TT + 2*gcol + 1];
      #pragma unroll
      for (int i = 0; i < 4; i++){
        int grow = grow0 + i;
        if (grow < NA){
          float ne = nrm[(size_t)b * TT + 2*grow];
          sc[((size_t)b * NA + grow) * NB + gcol] = acc[m][n][i] / (ne * no);
        }
      }
    }
  }
}

// ---------------- per-row max/argmax (first occurrence) ----------------
__global__ __launch_bounds__(64) void node_kernel(const float* __restrict__ sc,
                                                  float* __restrict__ nmax, int* __restrict__ nidx)
{
  int i = blockIdx.x, b = blockIdx.y, lane = threadIdx.x;
  const float* row = sc + ((size_t)b * NA + i) * NB;
  float v0 = row[lane];
  float v1 = row[lane + 64];
  float bv = v0; int bi = lane;
  if (v1 > bv){ bv = v1; bi = lane + 64; }
  #pragma unroll
  for (int m = 1; m < 64; m <<= 1){
    float ov = __shfl_xor(bv, m);
    int oi = __shfl_xor(bi, m);
    if (ov > bv || (ov == bv && oi < bi)){ bv = ov; bi = oi; }
  }
  if (lane == 0){
    if (i == 0){ nmax[(size_t)b * NA] = -INFINITY; nidx[(size_t)b * NA] = 0; }
    else { nmax[(size_t)b * NA + i] = bv; nidx[(size_t)b * NA + i] = bi; }
  }
}

// ------------- stable descending argsort + select -------------
__global__ __launch_bounds__(256) void rank_kernel(const float* __restrict__ nmax,
    const int* __restrict__ nidx, int* __restrict__ src, int* __restrict__ dst,
    int* __restrict__ unm, int* __restrict__ cnt)
{
  __shared__ float v[NA];
  __shared__ int rk[NA];
  __shared__ int edge[NA];
  __shared__ int cs[NB];
  int b = blockIdx.x, t = threadIdx.x;
  if (t < NA) v[t] = nmax[(size_t)b * NA + t];
  if (t < NB) cs[t] = 0;
  __syncthreads();
  if (t < NA){
    float vt = v[t]; int r = 0;
    for (int i = 0; i < NA; i++){
      float vi = v[i];
      r += (vi > vt) || (vi == vt && i < t);
    }
    rk[t] = r; edge[r] = t;
  }
  __syncthreads();
  if (t < RR){
    int s = edge[t];
    src[b * RR + t] = s;
    int d = nidx[(size_t)b * NA + s];
    dst[b * RR + t] = d;
    atomicAdd(&cs[d], 1);
  }
  if (t < NA && rk[t] >= RR){
    int p = 0;
    for (int i = 0; i < NA; i++) p += (i < t) && (rk[i] >= RR);
    unm[b * (NA - RR) + p] = t;
  }
  __syncthreads();
  if (t < NB) cnt[b * NB + t] = cs[t];
}

// ---------------- merge (reads hi/lo planes) ----------------
__global__ __launch_bounds__(256) void merge_kernel(const us* __restrict__ xh,
    const us* __restrict__ xl,
    const int* __restrict__ src, const int* __restrict__ dst, const int* __restrict__ unm,
    const int* __restrict__ cnt, float* __restrict__ xm)
{
  int u = blockIdx.x, b = blockIdx.y;
  int c = threadIdx.x * 4;
  const us* xhb = xh + (size_t)b * TT * DD;
  const us* xlb = xl + (size_t)b * TT * DD;
  float4 acc;
  if (u < NA - RR){
    int ts = 2 * unm[b * (NA - RR) + u];
    s4v h = *(const s4v*)(xhb + (size_t)ts * DD + c);
    s4v l = *(const s4v*)(xlb + (size_t)ts * DD + c);
    acc.x = bf2f((us)h[0]) + bf2f((us)l[0]);
    acc.y = bf2f((us)h[1]) + bf2f((us)l[1]);
    acc.z = bf2f((us)h[2]) + bf2f((us)l[2]);
    acc.w = bf2f((us)h[3]) + bf2f((us)l[3]);
  } else {
    int j = u - (NA - RR);
    s4v h = *(const s4v*)(xhb + (size_t)(2*j + 1) * DD + c);
    s4v l = *(const s4v*)(xlb + (size_t)(2*j + 1) * DD + c);
    acc.x = bf2f((us)h[0]) + bf2f((us)l[0]);
    acc.y = bf2f((us)h[1]) + bf2f((us)l[1]);
    acc.z = bf2f((us)h[2]) + bf2f((us)l[2]);
    acc.w = bf2f((us)h[3]) + bf2f((us)l[3]);
    #pragma unroll
    for (int k2 = 0; k2 < RR; k2++){
      if (dst[b * RR + k2] == j){
        int ts = 2 * src[b * RR + k2];
        s4v ah4 = *(const s4v*)(xhb + (size_t)ts * DD + c);
        s4v al4 = *(const s4v*)(xlb + (size_t)ts * DD + c);
        acc.x += bf2f((us)ah4[0]) + bf2f((us)al4[0]);
        acc.y += bf2f((us)ah4[1]) + bf2f((us)al4[1]);
        acc.z += bf2f((us)ah4[2]) + bf2f((us)al4[2]);
        acc.w += bf2f((us)ah4[3]) + bf2f((us)al4[3]);
      }
    }
    float inv = 1.0f / (float)(1 + cnt[b * NB + j]);
    acc.x *= inv; acc.y *= inv; acc.z *= inv; acc.w *= inv;
  }
  *(float4*)(xm + ((size_t)b * TMM + u) * DD + c) = acc;
}

// ---------------- launch ----------------
extern "C" void kernel_launch(void* const* d_in, const int* in_sizes, int n_in,
                              void* d_out, int out_size, void* d_ws, size_t ws_size,
                              hipStream_t stream)
{
  (void)in_sizes; (void)n_in; (void)out_size;
  const float* hidden = (const float*)d_in[0];
  const float* ln1_g  = (const float*)d_in[1];
  const float* ln1_b  = (const float*)d_in[2];
  const float* Wq = (const float*)d_in[3];
  const float* bq = (const float*)d_in[4];
  const float* Wk = (const float*)d_in[5];
  const float* bk = (const float*)d_in[6];
  const float* Wv = (const float*)d_in[7];
  const float* bv = (const float*)d_in[8];
  const float* Wo = (const float*)d_in[9];
  const float* bo = (const float*)d_in[10];
  const float* ln2_g = (const float*)d_in[11];
  const float* ln2_b = (const float*)d_in[12];
  const float* W1 = (const float*)d_in[13];
  const float* b1 = (const float*)d_in[14];
  const float* W2 = (const float*)d_in[15];
  const float* b2 = (const float*)d_in[16];

  char* base = (char*)d_ws;
  const size_t PE = (size_t)M1 * DD;          // plane elements
  const size_t PL = PE * sizeof(us);          // 33,685,504 B per plane
  us* qh = (us*)base;          us* ql = qh + PE;        // s0; attn O in-place
  us* kh = (us*)(base + 2*PL); us* kl = kh + PE;        // s1; later xbh/xbl planes
  us* vh = (us*)(base + 4*PL); us* vl = vh + PE;        // s2; later match scratch
  us* wts = (us*)(base + 6*PL);
  const size_t WD = (size_t)DD * DD;
  us* wqh = wts;
  us* wkh = wqh + WD;
  us* wvh = wkh + WD;
  us* wql = wvh + WD;
  us* wkl = wql + WD;
  us* wvl = wkl + WD;
  us* woh = wvl + WD;
  us* wol = woh + WD;
  us* w1h = wol + WD;
  us* w2h = w1h + (size_t)DD * FF;
  float* lnst1 = (float*)(w2h + (size_t)FF * DD);
  float* c1p   = lnst1 + 2 * M1;
  float* c2p   = c1p + 3072;                  // layout end = 235,823,616 B
  const size_t BASE_END = 235823616ull;
  us* hh = (us*)(base + BASE_END);            // optional pre-split hidden planes
  us* hl = hh + PE;
  const bool deep = ws_size >= BASE_END + 2*PL;   // 303,194,624 B
  us* xbh = (us*)(base + 2*PL);               // x = attn+resid as hi/lo planes (over kh/kl)
  us* xbl = xbh + PE;
  float* nrm   = (float*)(base + 4*PL);
  float* sc    = nrm + M1;
  float* nmaxp = sc + (size_t)BB * NA * NB;
  int*   nidxp = (int*)(nmaxp + BB * NA);
  int*   srcI  = nidxp + BB * NA;
  int*   dstI  = srcI + BB * RR;
  int*   unmI  = dstI + BB * RR;
  int*   cntI  = unmI + BB * (NA - RR);
  us*    xh2   = (us*)(base + 4*PL + (size_t)8*1024*1024);
  float* lnst2 = (float*)(base + 4*PL + (size_t)48*1024*1024);
  float* xm = (float*)d_out;
  us* mid = (us*)base;

  dim3 tb32(32, 8);
  wt_kernel<<<dim3(DD/32, DD/32), tb32, 0, stream>>>(Wq, wqh, wql, ln1_g, DD, DD);
  wt_kernel<<<dim3(DD/32, DD/32), tb32, 0, stream>>>(Wk, wkh, wkl, ln1_g, DD, DD);
  wt_kernel<<<dim3(DD/32, DD/32), tb32, 0, stream>>>(Wv, wvh, wvl, ln1_g, DD, DD);
  wt_kernel<<<dim3(DD/32, DD/32), tb32, 0, stream>>>(Wo, woh, wol, nullptr, DD, DD);
  wt_kernel<<<dim3(FF/32, DD/32), tb32, 0, stream>>>(W1, w1h, nullptr, nullptr, DD, FF);
  wt_kernel<<<dim3(DD/32, FF/32), tb32, 0, stream>>>(W2, w2h, nullptr, nullptr, FF, DD);

  qc_kernel<<<48, 256, 0, stream>>>(Wq, Wk, Wv, ln1_g, ln1_b, c1p, c2p);
  lnstats_kernel<<<M1, 64, 0, stream>>>(hidden, lnst1);

  if (deep){
    hsplit_kernel<<<M1, 256, 0, stream>>>(hidden, hh, hl);
    qkvp_kernel<<<dim3(3072/256, (M1 + 127)/128), 512, 0, stream>>>(hh, hl, wqh, wql,
        bq, bk, bv, lnst1, c1p, c2p, qh, ql, kh, kl, vh, vl);
  } else {
    qkv_kernel<<<dim3(3072/256, (M1 + 127)/128), 512, 0, stream>>>(hidden, wqh, wql,
        bq, bk, bv, lnst1, c1p, c2p, qh, ql, kh, kl, vh, vl);
  }

  attn_flash_kernel<<<BB*HH, 512, 0, stream>>>(qh, ql, kh, kl, vh, vl, qh, ql);

  // Wo: gather head-major O planes; write x as hi/lo planes (over dead kh/kl)
  gemm2_kernel<2,1,3><<<dim3(DD/128, (M1 + 127)/128), 256, 0, stream>>>(qh, ql, woh, wol,
      bo, hidden, xbh, xbl, M1, DD, DD);

  norms_kernel<<<M1, 64, 0, stream>>>(xbh, xbl, nrm);
  scores8_kernel<<<dim3(2, BB), 256, 0, stream>>>(xbh, xbl, nrm, sc);
  node_kernel<<<dim3(NA, BB), 64, 0, stream>>>(sc, nmaxp, nidxp);
  rank_kernel<<<BB, 256, 0, stream>>>(nmaxp, nidxp, srcI, dstI, unmI, cntI);
  merge_kernel<<<dim3(TMM, BB), 256, 0, stream>>>(xbh, xbl, srcI, dstI, unmI, cntI, xm);

  lnstats_kernel<<<M2, 64, 0, stream>>>(xm, lnst2);
  lncvt_kernel<<<M2, 256, 0, stream>>>(xm, lnst2, ln2_g, ln2_b, xh2);

  gemm8p_kernel<2><<<dim3(FF/256, (M2 + 255)/256), 512, 0, stream>>>(xh2, w1h,
      b1, nullptr, mid, M2, FF, DD);
  gemm8p_kernel<1><<<dim3(DD/256, (M2 + 255)/256), 512, 0, stream>>>(mid, w2h,
      b2, xm, (float*)d_out, M2, DD, FF);
}